// Round 4
// baseline (13881.287 us; speedup 1.0000x reference)
//
#include <hip/hip_runtime.h>
#include <cstdint>

// ---------------------------------------------------------------------------
// Autoformer forward. Internal compute f32. Input/output dtype (f32 vs bf16)
// detected at runtime on device from x_mark_enc (all-ones): first u32 ==
// 0x3F800000 -> f32, else (0x3F803F80) -> bf16. External tensors are passed
// as (base pointer, ELEMENT offset); each kernel applies the offset after
// branching on the flag, so host code never needs to know the dtype.
//
// B=32, L=1024, C_IN=21, D=512, H=8, E=64, D_FF=2048, layers=3, MA_K=25, topk=6
//
// Workspace (bytes), total ~144.2 MiB:
//   X    @ 0          : [32,1024,512] f32 activation / FFN hidden / OUT
//   S2   @ 67108864   : scratch (V / decomp / XH)
//   QC   @ 134217728  : [4,1024,512] f32 Q chunk / agg chunk
//   KC   @ 142606336  : [4,1024,512] f32 K chunk
//   MV   @ 150994944  : [32,1024] f32 mean_value
//   WGT  @ 151126016  : [32,6] f32 softmaxed weights
//   DLY  @ 151127040  : [32,6] int delays
//   CM   @ 151128064  : [32,512] f32 column means
//   PB   @ 151193600  : [32,10,16] f32 proj partials
//   FLAG @ 151214080  : int dtype flag (1 = f32 inputs)
// ---------------------------------------------------------------------------

using u16 = unsigned short;

#define BB 32
#define LL 1024
#define DD 512
#define DFF 2048

__device__ __forceinline__ float bf2f(u16 u) {
  union { uint32_t i; float f; } v; v.i = ((uint32_t)u) << 16; return v.f;
}
__device__ __forceinline__ u16 f2bf(float f) {
  union { float f; uint32_t i; } v; v.f = f;
  uint32_t r = (v.i + 0x7FFFu + ((v.i >> 16) & 1u)) >> 16;
  return (u16)r;
}
__device__ __forceinline__ float ldi(const void* p, long i, int isf) {
  return isf ? ((const float*)p)[i] : bf2f(((const u16*)p)[i]);
}
__device__ __forceinline__ float gelu_f(float x) {
  return 0.5f * x * (1.0f + erff(x * 0.70710678118654752440f));
}

__global__ void detect_k(const uint32_t* __restrict__ mark, int* __restrict__ FLAG) {
  if (threadIdx.x == 0) FLAG[0] = (mark[0] == 0x3F800000u) ? 1 : 0;
}

// Conv1d circular embedding. grid (L/16, B), block 256
__global__ __launch_bounds__(256) void conv_embed_k(
    const void* __restrict__ xe, const void* __restrict__ w,
    float* __restrict__ X, const int* __restrict__ FLAG) {
  const int isf = *FLAG;
  int b = blockIdx.y;
  int l0 = blockIdx.x * 16;
  __shared__ float xs[18][21];
  int tid = threadIdx.x;
  for (int i = tid; i < 18 * 21; i += 256) {
    int r = i / 21, c = i % 21;
    int row = (l0 - 1 + r + LL) & (LL - 1);
    xs[r][c] = ldi(xe, ((long)b * LL + row) * 21 + c, isf);
  }
  __syncthreads();
  for (int d = tid; d < DD; d += 256) {
    float acc[16];
#pragma unroll
    for (int ll = 0; ll < 16; ll++) acc[ll] = 0.0f;
    for (int c = 0; c < 21; c++) {
#pragma unroll
      for (int t = 0; t < 3; t++) {
        float wv = ldi(w, (long)d * 63 + c * 3 + t, isf);
#pragma unroll
        for (int ll = 0; ll < 16; ll++) acc[ll] += wv * xs[t + ll][c];
      }
    }
    for (int ll = 0; ll < 16; ll++)
      X[((long)b * LL + l0 + ll) * DD + d] = acc[ll];
  }
}

// Generic GEMM: C[M,N] = act( A[M,K] @ W[N,K]^T + bias + R ).
// W/bias are external (base + element offset, dtype via FLAG).
// FLAGS: 1=bias, 2=gelu, 4=residual. tile 128x128, BK=16, 256 thr, 8x8/thr.
template <int FLAGS>
__global__ __launch_bounds__(256) void gemm_f32(
    const float* __restrict__ A, const void* __restrict__ Wbase, long wOff,
    const void* __restrict__ biasBase, long bOff, const float* __restrict__ R,
    float* __restrict__ C, int M, int N, int K, const int* __restrict__ FLAG) {
  constexpr bool HAS_BIAS = (FLAGS & 1) != 0;
  constexpr bool DO_GELU = (FLAGS & 2) != 0;
  constexpr bool DO_RES = (FLAGS & 4) != 0;
  const int isf = *FLAG;
  __shared__ float As[16][132];
  __shared__ float Bs[16][132];
  const int n0 = blockIdx.x * 128;
  const int m0 = blockIdx.y * 128;
  const int tid = threadIdx.x;
  const int tx = tid & 15, ty = tid >> 4;
  const int lr = tid >> 1;
  const int lkq = (tid & 1) * 8;
  float acc[8][8] = {};
  for (int k0 = 0; k0 < K; k0 += 16) {
    const float* ap = A + (long)(m0 + lr) * K + (k0 + lkq);
    float4 a0 = *(const float4*)ap;
    float4 a1 = *(const float4*)(ap + 4);
    float wv[8];
    long woff = wOff + (long)(n0 + lr) * K + (k0 + lkq);
    if (isf) {
      const float* wp = (const float*)Wbase + woff;
      float4 w0 = *(const float4*)wp;
      float4 w1 = *(const float4*)(wp + 4);
      wv[0] = w0.x; wv[1] = w0.y; wv[2] = w0.z; wv[3] = w0.w;
      wv[4] = w1.x; wv[5] = w1.y; wv[6] = w1.z; wv[7] = w1.w;
    } else {
      const u16* wp = (const u16*)Wbase + woff;
      uint4 u = *(const uint4*)wp;
      wv[0] = bf2f((u16)(u.x & 0xffff)); wv[1] = bf2f((u16)(u.x >> 16));
      wv[2] = bf2f((u16)(u.y & 0xffff)); wv[3] = bf2f((u16)(u.y >> 16));
      wv[4] = bf2f((u16)(u.z & 0xffff)); wv[5] = bf2f((u16)(u.z >> 16));
      wv[6] = bf2f((u16)(u.w & 0xffff)); wv[7] = bf2f((u16)(u.w >> 16));
    }
    __syncthreads();
    As[lkq + 0][lr] = a0.x; As[lkq + 1][lr] = a0.y;
    As[lkq + 2][lr] = a0.z; As[lkq + 3][lr] = a0.w;
    As[lkq + 4][lr] = a1.x; As[lkq + 5][lr] = a1.y;
    As[lkq + 6][lr] = a1.z; As[lkq + 7][lr] = a1.w;
#pragma unroll
    for (int j = 0; j < 8; j++) Bs[lkq + j][lr] = wv[j];
    __syncthreads();
#pragma unroll
    for (int kk = 0; kk < 16; kk++) {
      float4 fa0 = *(const float4*)&As[kk][ty * 8];
      float4 fa1 = *(const float4*)&As[kk][ty * 8 + 4];
      float4 fb0 = *(const float4*)&Bs[kk][tx * 8];
      float4 fb1 = *(const float4*)&Bs[kk][tx * 8 + 4];
      float av[8] = {fa0.x, fa0.y, fa0.z, fa0.w, fa1.x, fa1.y, fa1.z, fa1.w};
      float bv[8] = {fb0.x, fb0.y, fb0.z, fb0.w, fb1.x, fb1.y, fb1.z, fb1.w};
#pragma unroll
      for (int i = 0; i < 8; i++)
#pragma unroll
        for (int j = 0; j < 8; j++) acc[i][j] = fmaf(av[i], bv[j], acc[i][j]);
    }
  }
  float bcol[8];
  if constexpr (HAS_BIAS) {
#pragma unroll
    for (int j = 0; j < 8; j++) bcol[j] = ldi(biasBase, bOff + n0 + tx * 8 + j, isf);
  }
#pragma unroll
  for (int i = 0; i < 8; i++) {
    int r = m0 + ty * 8 + i;
    long rowOff = (long)r * N + n0 + tx * 8;
    float v[8];
#pragma unroll
    for (int j = 0; j < 8; j++) {
      v[j] = acc[i][j];
      if constexpr (HAS_BIAS) v[j] += bcol[j];
    }
    if constexpr (DO_RES) {
#pragma unroll
      for (int j = 0; j < 8; j++) v[j] += R[rowOff + j];
    }
    if constexpr (DO_GELU) {
#pragma unroll
      for (int j = 0; j < 8; j++) v[j] = gelu_f(v[j]);
    }
    *(float4*)(C + rowOff) = make_float4(v[0], v[1], v[2], v[3]);
    *(float4*)(C + rowOff + 4) = make_float4(v[4], v[5], v[6], v[7]);
  }
}

// Fused Q.K^T + wrapped-diagonal mean reduction (internal f32 only).
// grid (8, 8, NB), block 256.  MV zeroed beforehand.
__global__ __launch_bounds__(256) void qkmv_k(
    const float* __restrict__ Q, const float* __restrict__ Km,
    float* __restrict__ MV) {
  __shared__ float As[16][132];
  __shared__ float Bs[16][132];
  __shared__ float diag[255];
  const int b = blockIdx.z;
  const float* Ab = Q + (long)b * LL * DD;
  const float* Wb = Km + (long)b * LL * DD;
  const int n0 = blockIdx.x * 128;
  const int m0 = blockIdx.y * 128;
  const int tid = threadIdx.x;
  const int tx = tid & 15, ty = tid >> 4;
  const int lr = tid >> 1;
  const int lkq = (tid & 1) * 8;
  if (tid < 255) diag[tid] = 0.0f;
  float acc[8][8] = {};
  for (int k0 = 0; k0 < DD; k0 += 16) {
    const float* ap = Ab + (long)(m0 + lr) * DD + (k0 + lkq);
    float4 a0 = *(const float4*)ap;
    float4 a1 = *(const float4*)(ap + 4);
    const float* wp = Wb + (long)(n0 + lr) * DD + (k0 + lkq);
    float4 w0 = *(const float4*)wp;
    float4 w1 = *(const float4*)(wp + 4);
    __syncthreads();
    As[lkq + 0][lr] = a0.x; As[lkq + 1][lr] = a0.y;
    As[lkq + 2][lr] = a0.z; As[lkq + 3][lr] = a0.w;
    As[lkq + 4][lr] = a1.x; As[lkq + 5][lr] = a1.y;
    As[lkq + 6][lr] = a1.z; As[lkq + 7][lr] = a1.w;
    Bs[lkq + 0][lr] = w0.x; Bs[lkq + 1][lr] = w0.y;
    Bs[lkq + 2][lr] = w0.z; Bs[lkq + 3][lr] = w0.w;
    Bs[lkq + 4][lr] = w1.x; Bs[lkq + 5][lr] = w1.y;
    Bs[lkq + 6][lr] = w1.z; Bs[lkq + 7][lr] = w1.w;
    __syncthreads();
#pragma unroll
    for (int kk = 0; kk < 16; kk++) {
      float4 fa0 = *(const float4*)&As[kk][ty * 8];
      float4 fa1 = *(const float4*)&As[kk][ty * 8 + 4];
      float4 fb0 = *(const float4*)&Bs[kk][tx * 8];
      float4 fb1 = *(const float4*)&Bs[kk][tx * 8 + 4];
      float av[8] = {fa0.x, fa0.y, fa0.z, fa0.w, fa1.x, fa1.y, fa1.z, fa1.w};
      float bv[8] = {fb0.x, fb0.y, fb0.z, fb0.w, fb1.x, fb1.y, fb1.z, fb1.w};
#pragma unroll
      for (int i = 0; i < 8; i++)
#pragma unroll
        for (int j = 0; j < 8; j++) acc[i][j] = fmaf(av[i], bv[j], acc[i][j]);
    }
  }
#pragma unroll
  for (int dl = -7; dl <= 7; dl++) {
    float t = 0.0f;
#pragma unroll
    for (int ii = 0; ii < 8; ii++) {
      int jj = ii - dl;
      if (jj >= 0 && jj < 8) t += acc[ii][jj];
    }
    atomicAdd(&diag[(ty - tx) * 8 + dl + 127], t);
  }
  __syncthreads();
  if (tid < 255) {
    int tau = (m0 - n0 + tid - 127 + LL) & (LL - 1);
    atomicAdd(&MV[(long)b * LL + tau], diag[tid] * (1.0f / 512.0f));
  }
}

// top-6 of MV[b,:] + softmax.  grid (32), block 256
__global__ __launch_bounds__(256) void topk_k(const float* __restrict__ MV,
                                              float* __restrict__ WGT,
                                              int* __restrict__ DLY) {
  int b = blockIdx.x;
  __shared__ float vals[LL];
  __shared__ float rv[256];
  __shared__ int ri[256];
  __shared__ float selv[6];
  int tid = threadIdx.x;
  for (int i = tid; i < LL; i += 256) vals[i] = MV[(long)b * LL + i];
  __syncthreads();
  for (int it = 0; it < 6; it++) {
    float bv = -1e30f;
    int bi = LL - 1;
    for (int i = tid; i < LL; i += 256) {
      float v = vals[i];
      if (v > bv || (v == bv && i < bi)) { bv = v; bi = i; }
    }
    rv[tid] = bv; ri[tid] = bi;
    __syncthreads();
    for (int st = 128; st > 0; st >>= 1) {
      if (tid < st) {
        float ov = rv[tid + st]; int oi = ri[tid + st];
        if (ov > rv[tid] || (ov == rv[tid] && oi < ri[tid])) {
          rv[tid] = ov; ri[tid] = oi;
        }
      }
      __syncthreads();
    }
    if (tid == 0) {
      selv[it] = rv[0];
      DLY[b * 6 + it] = ri[0];
      vals[ri[0]] = -1e30f;
    }
    __syncthreads();
  }
  if (tid == 0) {
    float mx = selv[0];
    float e[6], s = 0.0f;
    for (int i = 0; i < 6; i++) { e[i] = expf(selv[i] - mx); s += e[i]; }
    for (int i = 0; i < 6; i++) WGT[b * 6 + i] = e[i] / s;
  }
}

// time-delay aggregation (chunk-local pointers): grid (1024, NB), block 128
__global__ __launch_bounds__(128) void agg_k(const float* __restrict__ V,
                                             const float* __restrict__ WGT,
                                             const int* __restrict__ DLY,
                                             float* __restrict__ O) {
  int l = blockIdx.x, b = blockIdx.y;
  int tid = threadIdx.x;
  float w[6]; int dl[6];
#pragma unroll
  for (int i = 0; i < 6; i++) { w[i] = WGT[b * 6 + i]; dl[i] = DLY[b * 6 + i]; }
  long base = (long)b * LL * DD;
  int d = tid * 4;
  float ax = 0, ay = 0, az = 0, aw = 0;
#pragma unroll
  for (int i = 0; i < 6; i++) {
    int row = (l + dl[i]) & (LL - 1);
    float4 vv = *(const float4*)&V[base + (long)row * DD + d];
    ax += w[i] * vv.x; ay += w[i] * vv.y; az += w[i] * vv.z; aw += w[i] * vv.w;
  }
  *(float4*)&O[base + (long)l * DD + d] = make_float4(ax, ay, az, aw);
}

// series_decomp residual. grid (2, 16, 32), block 256
__global__ __launch_bounds__(256) void decomp_k(const float* __restrict__ Xin,
                                                float* __restrict__ Out) {
  int d = blockIdx.x * 256 + threadIdx.x;
  int l0 = blockIdx.y * 64;
  int b = blockIdx.z;
  const float* xb = Xin + (long)b * LL * DD + d;
  float* ob = Out + (long)b * LL * DD + d;
  float wsum = 0.0f;
  for (int j = l0 - 12; j <= l0 + 12; j++) {
    int jj = min(max(j, 0), LL - 1);
    wsum += xb[(long)jj * DD];
  }
  for (int l = l0; l < l0 + 64; l++) {
    float xv = xb[(long)l * DD];
    ob[(long)l * DD] = xv - wsum * (1.0f / 25.0f);
    int ja = min(l + 13, LL - 1);
    int jr = max(l - 12, 0);
    wsum += xb[(long)ja * DD] - xb[(long)jr * DD];
  }
}

// special layernorm. grid (1024,32), block 256
__global__ __launch_bounds__(256) void ln_k(const float* __restrict__ X,
                                            const void* __restrict__ g,
                                            const void* __restrict__ be,
                                            float* __restrict__ XH,
                                            const int* __restrict__ FLAG) {
  const int isf = *FLAG;
  int l = blockIdx.x, b = blockIdx.y;
  const float* xr = X + ((long)b * LL + l) * DD;
  int tid = threadIdx.x;
  float x0 = xr[tid], x1 = xr[tid + 256];
  __shared__ float rs[256], rq[256];
  rs[tid] = x0 + x1;
  rq[tid] = x0 * x0 + x1 * x1;
  __syncthreads();
  for (int st = 128; st > 0; st >>= 1) {
    if (tid < st) { rs[tid] += rs[tid + st]; rq[tid] += rq[tid + st]; }
    __syncthreads();
  }
  float mu = rs[0] * (1.0f / 512.0f);
  float var = rq[0] * (1.0f / 512.0f) - mu * mu;
  float rstd = rsqrtf(var + 1e-5f);
  float* o = XH + ((long)b * LL + l) * DD;
  o[tid] = (x0 - mu) * rstd * ldi(g, tid, isf) + ldi(be, tid, isf);
  o[tid + 256] = (x1 - mu) * rstd * ldi(g, tid + 256, isf) + ldi(be, tid + 256, isf);
}

// colmean. grid (2,32), block 256
__global__ __launch_bounds__(256) void colmean_k(const float* __restrict__ XH,
                                                 float* __restrict__ CM) {
  int d = blockIdx.x * 256 + threadIdx.x;
  int b = blockIdx.y;
  const float* p = XH + (long)b * LL * DD + d;
  float s = 0.0f;
  for (int l = 0; l < LL; l++) s += p[(long)l * DD];
  CM[(long)b * DD + d] = s * (1.0f / 1024.0f);
}

// OUT = gelu(XH - CM) * mark. grid (1024,32), block 256
__global__ __launch_bounds__(256) void geluout_k(const float* __restrict__ XH,
                                                 const float* __restrict__ CM,
                                                 const void* __restrict__ mark,
                                                 float* __restrict__ OUT,
                                                 const int* __restrict__ FLAG) {
  const int isf = *FLAG;
  int l = blockIdx.x, b = blockIdx.y;
  int tid = threadIdx.x;
  float mk = ldi(mark, (long)b * LL + l, isf);
  long off = ((long)b * LL + l) * DD;
#pragma unroll
  for (int h = 0; h < 2; h++) {
    int d = tid + h * 256;
    float v = XH[off + d] - CM[(long)b * DD + d];
    OUT[off + d] = gelu_f(v) * mk;
  }
}

// proj stage 1. grid (16, 10, 32), block 256
__global__ __launch_bounds__(256) void proj1_k(const float* __restrict__ OUT,
                                               const void* __restrict__ Wp,
                                               float* __restrict__ PB,
                                               const int* __restrict__ FLAG) {
  const int isf = *FLAG;
  int chunk = blockIdx.x, n = blockIdx.y, b = blockIdx.z;
  long e0 = (long)chunk * 32768;
  const float* xb = OUT + (long)b * 524288 + e0;
  long wbase = (long)n * 524288 + e0;
  int tid = threadIdx.x;
  float s = 0.0f;
  if (isf) {
    const float* wr = (const float*)Wp + wbase;
    for (int i = tid * 4; i < 32768; i += 1024) {
      float4 x = *(const float4*)&xb[i];
      float4 w = *(const float4*)&wr[i];
      s += x.x * w.x + x.y * w.y + x.z * w.z + x.w * w.w;
    }
  } else {
    const u16* wr = (const u16*)Wp + wbase;
    for (int i = tid * 4; i < 32768; i += 1024) {
      float4 x = *(const float4*)&xb[i];
      uint2 u = *(const uint2*)&wr[i];
      s += x.x * bf2f((u16)(u.x & 0xffff)) + x.y * bf2f((u16)(u.x >> 16)) +
           x.z * bf2f((u16)(u.y & 0xffff)) + x.w * bf2f((u16)(u.y >> 16));
    }
  }
  __shared__ float red[256];
  red[tid] = s;
  __syncthreads();
  for (int st = 128; st > 0; st >>= 1) {
    if (tid < st) red[tid] += red[tid + st];
    __syncthreads();
  }
  if (tid == 0) PB[((long)b * 10 + n) * 16 + chunk] = red[0];
}

// proj stage 2: logits -> out (dtype per FLAG). grid (1), block 320
__global__ __launch_bounds__(320) void proj2_k(const float* __restrict__ PB,
                                               const void* __restrict__ bp,
                                               void* __restrict__ out,
                                               const int* __restrict__ FLAG) {
  const int isf = *FLAG;
  int id = threadIdx.x;
  int b = id / 10, n = id % 10;
  float s = ldi(bp, n, isf);
  for (int c = 0; c < 16; c++) s += PB[((long)b * 10 + n) * 16 + c];
  if (isf) ((float*)out)[b * 10 + n] = s;
  else ((u16*)out)[b * 10 + n] = f2bf(s);
}

// ---------------------------------------------------------------------------
extern "C" void kernel_launch(void* const* d_in, const int* in_sizes, int n_in,
                              void* d_out, int out_size, void* d_ws, size_t ws_size,
                              hipStream_t stream) {
  const void* xe = d_in[0];
  const void* mark = d_in[1];
  const void* cw = d_in[2];
  const void* Wq = d_in[3];
  const void* bq = d_in[4];
  const void* Wk = d_in[5];
  const void* bk = d_in[6];
  const void* Wv = d_in[7];
  const void* bv = d_in[8];
  const void* Wo = d_in[9];
  const void* bo = d_in[10];
  const void* Wff1 = d_in[11];
  const void* Wff2 = d_in[12];
  const void* lng = d_in[13];
  const void* lnb = d_in[14];
  const void* Wp = d_in[15];
  const void* bp = d_in[16];

  char* ws = (char*)d_ws;
  float* X   = (float*)(ws + 0L);
  float* S2  = (float*)(ws + 67108864L);
  float* QC  = (float*)(ws + 134217728L);
  float* KC  = (float*)(ws + 142606336L);
  float* MV  = (float*)(ws + 150994944L);
  float* WGT = (float*)(ws + 151126016L);
  int*   DLY = (int*)(ws + 151127040L);
  float* CM  = (float*)(ws + 151128064L);
  float* PB  = (float*)(ws + 151193600L);
  int*  FLAG = (int*)(ws + 151214080L);

  const long AD = (long)LL * DD;  // 524288 floats per batch
  const int M = BB * LL;          // 32768

  detect_k<<<1, 64, 0, stream>>>((const uint32_t*)mark, FLAG);
  conv_embed_k<<<dim3(64, 32), 256, 0, stream>>>(xe, cw, X, FLAG);

  for (int l = 0; l < 3; l++) {
    const long oW = (long)l * DD * DD;    // element offsets per layer
    const long oB = (long)l * DD;
    const long oF1 = (long)l * DFF * DD;
    const long oF2 = (long)l * DD * DFF;

    // mean_value via fused Q.K^T diagonal reduction, 4-batch chunks
    hipMemsetAsync(MV, 0, (long)BB * LL * sizeof(float), stream);
    for (int cb = 0; cb < 8; cb++) {
      const float* xc = X + (long)cb * 4 * AD;
      gemm_f32<1><<<dim3(4, 32), 256, 0, stream>>>(
          xc, Wq, oW, bq, oB, nullptr, QC, 4096, DD, DD, FLAG);
      gemm_f32<1><<<dim3(4, 32), 256, 0, stream>>>(
          xc, Wk, oW, bk, oB, nullptr, KC, 4096, DD, DD, FLAG);
      qkmv_k<<<dim3(8, 8, 4), 256, 0, stream>>>(QC, KC, MV + (long)cb * 4 * LL);
    }
    topk_k<<<32, 256, 0, stream>>>(MV, WGT, DLY);

    // V (full) -> S2
    gemm_f32<1><<<dim3(4, 256), 256, 0, stream>>>(
        X, Wv, oW, bv, oB, nullptr, S2, M, DD, DD, FLAG);

    // agg (4-batch chunks) -> QC, then X += agg @ Wo^T + bo (in-place)
    for (int cb = 0; cb < 8; cb++) {
      agg_k<<<dim3(1024, 4), 128, 0, stream>>>(
          S2 + (long)cb * 4 * AD, WGT + cb * 24, DLY + cb * 24, QC);
      float* xc = X + (long)cb * 4 * AD;
      gemm_f32<5><<<dim3(4, 32), 256, 0, stream>>>(
          QC, Wo, oW, bo, oB, xc, xc, 4096, DD, DD, FLAG);
    }

    // x = decomp(x) -> S2   (X dead, reused as FFN hidden buffer)
    decomp_k<<<dim3(2, 16, 32), 256, 0, stream>>>(X, S2);

    // FFN per 8-batch chunk: hidden -> X region, result in-place S2
    for (int cb = 0; cb < 4; cb++) {
      float* xd = S2 + (long)cb * 8 * AD;
      gemm_f32<2><<<dim3(16, 64), 256, 0, stream>>>(
          xd, Wff1, oF1, nullptr, 0, nullptr, X, 8192, DFF, DD, FLAG);
      gemm_f32<4><<<dim3(4, 64), 256, 0, stream>>>(
          X, Wff2, oF2, nullptr, 0, xd, xd, 8192, DD, DFF, FLAG);
    }

    // x = decomp(S2) -> X (next layer input)
    decomp_k<<<dim3(2, 16, 32), 256, 0, stream>>>(S2, X);
  }

  // final special layernorm + gelu + mask + projection
  ln_k<<<dim3(1024, 32), 256, 0, stream>>>(X, lng, lnb, S2, FLAG);
  colmean_k<<<dim3(2, 32), 256, 0, stream>>>(S2, CM);
  geluout_k<<<dim3(1024, 32), 256, 0, stream>>>(S2, CM, mark, X, FLAG);
  proj1_k<<<dim3(16, 10, 32), 256, 0, stream>>>(X, Wp, PB, FLAG);
  proj2_k<<<1, 320, 0, stream>>>(PB, bp, d_out, FLAG);
}

// Round 7
// 7425.006 us; speedup vs baseline: 1.8695x; 1.8695x over previous
//
#include <hip/hip_runtime.h>
#include <cstdint>

// ---------------------------------------------------------------------------
// Autoformer forward — hybrid precision:
//   * delay-selection path (Q-proj, K-proj, Q.K^T diagonal reduce, top-k)
//     in exact f32 (R4-verified kernels) — top-k is discretely sensitive.
//   * all other GEMMs (V, Wo, FFN1, FFN2) on fp16 MFMA, f32 accumulate.
// Inputs f32 (runtime-detected from x_mark_enc; bf16 fallback kept).
//
// B=32, L=1024, C_IN=21, D=512, H=8, E=64, D_FF=2048, layers=3, MA_K=25, topk=6
//
// Workspace (bytes), total ~149.1 MB:
//   X    @ 0          : [32,1024,512] f32 residual; FFN phase: Hb fp16 hidden
//   S2   @ 67108864   : phase-aliased 64 MiB:
//                         QK phase:  QC32 f32 (8Mi) | KC32 f32 (8Mi)
//                         attn phase: Xh fp16 (32Mi) | AGh fp16 (32Mi)
//                         FFN phase:  XD f32 full (decomp out, FFN in-place)
//   Ph   @ 134217728  : 8 MiB fp16 chunk (V chunk / XDh chunk)
//   WB   @ 142606336  : fp16 weights for V/Wo/FFN (per layer)
//   MV   @ 148897792  : [32,1024] f32 mean_value
//   WGT  @ 149028864  : [32,6] f32
//   DLY  @ 149029888  : [32,6] int
//   CM   @ 149030912  : [32,512] f32
//   PB   @ 149096448  : [32,10,16] f32
//   FLAG @ 149116928  : int dtype flag
// ---------------------------------------------------------------------------

using u16 = unsigned short;
typedef _Float16 f16x8 __attribute__((ext_vector_type(8)));
typedef float f32x4 __attribute__((ext_vector_type(4)));

#define BB 32
#define LL 1024
#define DD 512
#define DFF 2048

__device__ __forceinline__ float bf2f(u16 u) {
  union { uint32_t i; float f; } v; v.i = ((uint32_t)u) << 16; return v.f;
}
__device__ __forceinline__ u16 f2bf(float f) {
  union { float f; uint32_t i; } v; v.f = f;
  uint32_t r = (v.i + 0x7FFFu + ((v.i >> 16) & 1u)) >> 16;
  return (u16)r;
}
__device__ __forceinline__ float ldi(const void* p, long i, int isf) {
  return isf ? ((const float*)p)[i] : bf2f(((const u16*)p)[i]);
}
__device__ __forceinline__ float gelu_f(float x) {
  return 0.5f * x * (1.0f + erff(x * 0.70710678118654752440f));
}

union H8 { f16x8 v; uint4 u; _Float16 h[8]; };
union H4 { uint2 u; _Float16 h[4]; };

__global__ void detect_k(const uint32_t* __restrict__ mark, int* __restrict__ FLAG) {
  if (threadIdx.x == 0) FLAG[0] = (mark[0] == 0x3F800000u) ? 1 : 0;
}

// ---------------------------------------------------------------------------
// Conv1d circular embedding. grid (L/16, B), block 256
// ---------------------------------------------------------------------------
__global__ __launch_bounds__(256) void conv_embed_k(
    const void* __restrict__ xe, const void* __restrict__ w,
    float* __restrict__ X, const int* __restrict__ FLAG) {
  const int isf = *FLAG;
  int b = blockIdx.y;
  int l0 = blockIdx.x * 16;
  __shared__ float xs[18][21];
  int tid = threadIdx.x;
  for (int i = tid; i < 18 * 21; i += 256) {
    int r = i / 21, c = i % 21;
    int row = (l0 - 1 + r + LL) & (LL - 1);
    xs[r][c] = ldi(xe, ((long)b * LL + row) * 21 + c, isf);
  }
  __syncthreads();
  for (int d = tid; d < DD; d += 256) {
    float acc[16];
#pragma unroll
    for (int ll = 0; ll < 16; ll++) acc[ll] = 0.0f;
    for (int c = 0; c < 21; c++) {
#pragma unroll
      for (int t = 0; t < 3; t++) {
        float wv = ldi(w, (long)d * 63 + c * 3 + t, isf);
#pragma unroll
        for (int ll = 0; ll < 16; ll++) acc[ll] += wv * xs[t + ll][c];
      }
    }
    for (int ll = 0; ll < 16; ll++)
      X[((long)b * LL + l0 + ll) * DD + d] = acc[ll];
  }
}

// ---------------------------------------------------------------------------
// f32 VALU GEMM (R4-verified): C[M,N] = A[M,K] @ W[N,K]^T + bias
// W/bias external (base + element offset, dtype via FLAG).
// tile 128x128, BK=16, 256 thr, 8x8/thr.  grid (N/128, M/128)
// ---------------------------------------------------------------------------
__global__ __launch_bounds__(256) void gemm_f32b(
    const float* __restrict__ A, const void* __restrict__ Wbase, long wOff,
    const void* __restrict__ biasBase, long bOff,
    float* __restrict__ C, int M, int N, int K, const int* __restrict__ FLAG) {
  const int isf = *FLAG;
  __shared__ float As[16][132];
  __shared__ float Bs[16][132];
  const int n0 = blockIdx.x * 128;
  const int m0 = blockIdx.y * 128;
  const int tid = threadIdx.x;
  const int tx = tid & 15, ty = tid >> 4;
  const int lr = tid >> 1;
  const int lkq = (tid & 1) * 8;
  float acc[8][8] = {};
  for (int k0 = 0; k0 < K; k0 += 16) {
    const float* ap = A + (long)(m0 + lr) * K + (k0 + lkq);
    float4 a0 = *(const float4*)ap;
    float4 a1 = *(const float4*)(ap + 4);
    float wv[8];
    long woff = wOff + (long)(n0 + lr) * K + (k0 + lkq);
    if (isf) {
      const float* wp = (const float*)Wbase + woff;
      float4 w0 = *(const float4*)wp;
      float4 w1 = *(const float4*)(wp + 4);
      wv[0] = w0.x; wv[1] = w0.y; wv[2] = w0.z; wv[3] = w0.w;
      wv[4] = w1.x; wv[5] = w1.y; wv[6] = w1.z; wv[7] = w1.w;
    } else {
      const u16* wp = (const u16*)Wbase + woff;
      uint4 u = *(const uint4*)wp;
      wv[0] = bf2f((u16)(u.x & 0xffff)); wv[1] = bf2f((u16)(u.x >> 16));
      wv[2] = bf2f((u16)(u.y & 0xffff)); wv[3] = bf2f((u16)(u.y >> 16));
      wv[4] = bf2f((u16)(u.z & 0xffff)); wv[5] = bf2f((u16)(u.z >> 16));
      wv[6] = bf2f((u16)(u.w & 0xffff)); wv[7] = bf2f((u16)(u.w >> 16));
    }
    __syncthreads();
    As[lkq + 0][lr] = a0.x; As[lkq + 1][lr] = a0.y;
    As[lkq + 2][lr] = a0.z; As[lkq + 3][lr] = a0.w;
    As[lkq + 4][lr] = a1.x; As[lkq + 5][lr] = a1.y;
    As[lkq + 6][lr] = a1.z; As[lkq + 7][lr] = a1.w;
#pragma unroll
    for (int j = 0; j < 8; j++) Bs[lkq + j][lr] = wv[j];
    __syncthreads();
#pragma unroll
    for (int kk = 0; kk < 16; kk++) {
      float4 fa0 = *(const float4*)&As[kk][ty * 8];
      float4 fa1 = *(const float4*)&As[kk][ty * 8 + 4];
      float4 fb0 = *(const float4*)&Bs[kk][tx * 8];
      float4 fb1 = *(const float4*)&Bs[kk][tx * 8 + 4];
      float av[8] = {fa0.x, fa0.y, fa0.z, fa0.w, fa1.x, fa1.y, fa1.z, fa1.w};
      float bv[8] = {fb0.x, fb0.y, fb0.z, fb0.w, fb1.x, fb1.y, fb1.z, fb1.w};
#pragma unroll
      for (int i = 0; i < 8; i++)
#pragma unroll
        for (int j = 0; j < 8; j++) acc[i][j] = fmaf(av[i], bv[j], acc[i][j]);
    }
  }
  float bcol[8];
#pragma unroll
  for (int j = 0; j < 8; j++) bcol[j] = ldi(biasBase, bOff + n0 + tx * 8 + j, isf);
#pragma unroll
  for (int i = 0; i < 8; i++) {
    int r = m0 + ty * 8 + i;
    long rowOff = (long)r * N + n0 + tx * 8;
    float v[8];
#pragma unroll
    for (int j = 0; j < 8; j++) v[j] = acc[i][j] + bcol[j];
    *(float4*)(C + rowOff) = make_float4(v[0], v[1], v[2], v[3]);
    *(float4*)(C + rowOff + 4) = make_float4(v[4], v[5], v[6], v[7]);
  }
}

// ---------------------------------------------------------------------------
// f32 fused Q.K^T + wrapped-diagonal mean reduction (R4-verified):
//   MV[b,tau] += (1/512) * sum_t Q[b,(t+tau)%L,:] . K[b,t,:]
// grid (8, 8, NB), block 256.  MV (chunk-offset) zeroed beforehand.
// ---------------------------------------------------------------------------
__global__ __launch_bounds__(256) void qkmv_k(
    const float* __restrict__ Q, const float* __restrict__ Km,
    float* __restrict__ MV) {
  __shared__ float As[16][132];
  __shared__ float Bs[16][132];
  __shared__ float diag[255];
  const int b = blockIdx.z;
  const float* Ab = Q + (long)b * LL * DD;
  const float* Wb = Km + (long)b * LL * DD;
  const int n0 = blockIdx.x * 128;
  const int m0 = blockIdx.y * 128;
  const int tid = threadIdx.x;
  const int tx = tid & 15, ty = tid >> 4;
  const int lr = tid >> 1;
  const int lkq = (tid & 1) * 8;
  if (tid < 255) diag[tid] = 0.0f;
  float acc[8][8] = {};
  for (int k0 = 0; k0 < DD; k0 += 16) {
    const float* ap = Ab + (long)(m0 + lr) * DD + (k0 + lkq);
    float4 a0 = *(const float4*)ap;
    float4 a1 = *(const float4*)(ap + 4);
    const float* wp = Wb + (long)(n0 + lr) * DD + (k0 + lkq);
    float4 w0 = *(const float4*)wp;
    float4 w1 = *(const float4*)(wp + 4);
    __syncthreads();
    As[lkq + 0][lr] = a0.x; As[lkq + 1][lr] = a0.y;
    As[lkq + 2][lr] = a0.z; As[lkq + 3][lr] = a0.w;
    As[lkq + 4][lr] = a1.x; As[lkq + 5][lr] = a1.y;
    As[lkq + 6][lr] = a1.z; As[lkq + 7][lr] = a1.w;
    Bs[lkq + 0][lr] = w0.x; Bs[lkq + 1][lr] = w0.y;
    Bs[lkq + 2][lr] = w0.z; Bs[lkq + 3][lr] = w0.w;
    Bs[lkq + 4][lr] = w1.x; Bs[lkq + 5][lr] = w1.y;
    Bs[lkq + 6][lr] = w1.z; Bs[lkq + 7][lr] = w1.w;
    __syncthreads();
#pragma unroll
    for (int kk = 0; kk < 16; kk++) {
      float4 fa0 = *(const float4*)&As[kk][ty * 8];
      float4 fa1 = *(const float4*)&As[kk][ty * 8 + 4];
      float4 fb0 = *(const float4*)&Bs[kk][tx * 8];
      float4 fb1 = *(const float4*)&Bs[kk][tx * 8 + 4];
      float av[8] = {fa0.x, fa0.y, fa0.z, fa0.w, fa1.x, fa1.y, fa1.z, fa1.w};
      float bv[8] = {fb0.x, fb0.y, fb0.z, fb0.w, fb1.x, fb1.y, fb1.z, fb1.w};
#pragma unroll
      for (int i = 0; i < 8; i++)
#pragma unroll
        for (int j = 0; j < 8; j++) acc[i][j] = fmaf(av[i], bv[j], acc[i][j]);
    }
  }
#pragma unroll
  for (int dl = -7; dl <= 7; dl++) {
    float t = 0.0f;
#pragma unroll
    for (int ii = 0; ii < 8; ii++) {
      int jj = ii - dl;
      if (jj >= 0 && jj < 8) t += acc[ii][jj];
    }
    atomicAdd(&diag[(ty - tx) * 8 + dl + 127], t);
  }
  __syncthreads();
  if (tid < 255) {
    int tau = (m0 - n0 + tid - 127 + LL) & (LL - 1);
    atomicAdd(&MV[(long)b * LL + tau], diag[tid] * (1.0f / 512.0f));
  }
}

// ---------------------------------------------------------------------------
// convert f32 -> fp16, 8 elems/thread. grid = n/2048
// ---------------------------------------------------------------------------
__global__ __launch_bounds__(256) void acvt_k(const float* __restrict__ src,
                                              _Float16* __restrict__ dst, int n) {
  long i = ((long)blockIdx.x * 256 + threadIdx.x) * 8;
  if (i >= n) return;
  float4 a = *(const float4*)(src + i);
  float4 b = *(const float4*)(src + i + 4);
  H8 r;
  r.h[0] = (_Float16)a.x; r.h[1] = (_Float16)a.y;
  r.h[2] = (_Float16)a.z; r.h[3] = (_Float16)a.w;
  r.h[4] = (_Float16)b.x; r.h[5] = (_Float16)b.y;
  r.h[6] = (_Float16)b.z; r.h[7] = (_Float16)b.w;
  *(uint4*)(dst + i) = r.u;
}

// convert external weight (f32 or bf16 per FLAG) -> fp16
__global__ __launch_bounds__(256) void wcvt_k(const void* __restrict__ src, long off,
                                              _Float16* __restrict__ dst, int n,
                                              const int* __restrict__ FLAG) {
  const int isf = *FLAG;
  long i = ((long)blockIdx.x * 256 + threadIdx.x) * 8;
  if (i >= n) return;
  H8 r;
  if (isf) {
    const float* s = (const float*)src + off + i;
    float4 a = *(const float4*)s;
    float4 b = *(const float4*)(s + 4);
    r.h[0] = (_Float16)a.x; r.h[1] = (_Float16)a.y;
    r.h[2] = (_Float16)a.z; r.h[3] = (_Float16)a.w;
    r.h[4] = (_Float16)b.x; r.h[5] = (_Float16)b.y;
    r.h[6] = (_Float16)b.z; r.h[7] = (_Float16)b.w;
  } else {
    const u16* s = (const u16*)src + off + i;
    uint4 u = *(const uint4*)s;
    r.h[0] = (_Float16)bf2f((u16)(u.x & 0xffff));
    r.h[1] = (_Float16)bf2f((u16)(u.x >> 16));
    r.h[2] = (_Float16)bf2f((u16)(u.y & 0xffff));
    r.h[3] = (_Float16)bf2f((u16)(u.y >> 16));
    r.h[4] = (_Float16)bf2f((u16)(u.z & 0xffff));
    r.h[5] = (_Float16)bf2f((u16)(u.z >> 16));
    r.h[6] = (_Float16)bf2f((u16)(u.w & 0xffff));
    r.h[7] = (_Float16)bf2f((u16)(u.w >> 16));
  }
  *(uint4*)(dst + i) = r.u;
}

// ---------------------------------------------------------------------------
// fp16 MFMA GEMM: C[M,N] = act( A[M,K] @ W[N,K]^T + bias + R )
// FLAGS: 1=bias 2=gelu 4=residual 8=out-fp16
// tile 128x128, BK=32, 256 threads (4 waves 2x2), 4x4 16x16x32 frags/wave.
// ---------------------------------------------------------------------------
template <int FLAGS>
__global__ __launch_bounds__(256) void gemm_h(
    const _Float16* __restrict__ A, const _Float16* __restrict__ W,
    const void* __restrict__ biasBase, long bOff,
    const float* __restrict__ R, void* __restrict__ Cout,
    int M, int N, int K, const int* __restrict__ FLAG) {
  constexpr bool HAS_BIAS = (FLAGS & 1) != 0;
  constexpr bool DO_GELU = (FLAGS & 2) != 0;
  constexpr bool DO_RES = (FLAGS & 4) != 0;
  constexpr bool OUT_H = (FLAGS & 8) != 0;
  __shared__ __align__(16) _Float16 As[128 * 32];
  __shared__ __align__(16) _Float16 Bs[128 * 32];
  const int n0 = blockIdx.x * 128, m0 = blockIdx.y * 128;
  const int tid = threadIdx.x;
  const int lane = tid & 63, wvi = tid >> 6;
  const int wm = (wvi >> 1) * 64, wn = (wvi & 1) * 64;
  const int l15 = lane & 15, quad = lane >> 4;
  const int srow = tid >> 1;
  const int sseg = (tid & 1) * 2;
  const int sg = (srow >> 1) & 3;
  const int wo1 = srow * 32 + ((sseg ^ sg) * 8);
  const int wo2 = srow * 32 + (((sseg + 1) ^ sg) * 8);
  const _Float16* aptr = A + (long)(m0 + srow) * K + sseg * 8;
  const _Float16* wptr = W + (long)(n0 + srow) * K + sseg * 8;
  f32x4 acc[4][4];
#pragma unroll
  for (int i = 0; i < 4; i++)
#pragma unroll
    for (int j = 0; j < 4; j++) acc[i][j] = (f32x4){0.f, 0.f, 0.f, 0.f};
  for (int k0 = 0; k0 < K; k0 += 32) {
    uint4 av1 = *(const uint4*)(aptr + k0);
    uint4 av2 = *(const uint4*)(aptr + k0 + 8);
    uint4 wv1 = *(const uint4*)(wptr + k0);
    uint4 wv2 = *(const uint4*)(wptr + k0 + 8);
    __syncthreads();
    *(uint4*)&As[wo1] = av1; *(uint4*)&As[wo2] = av2;
    *(uint4*)&Bs[wo1] = wv1; *(uint4*)&Bs[wo2] = wv2;
    __syncthreads();
    f16x8 af[4], bfr[4];
#pragma unroll
    for (int mi = 0; mi < 4; mi++) {
      int r = wm + mi * 16 + l15;
      af[mi] = *(const f16x8*)&As[r * 32 + ((quad ^ ((r >> 1) & 3)) * 8)];
    }
#pragma unroll
    for (int ni = 0; ni < 4; ni++) {
      int r = wn + ni * 16 + l15;
      bfr[ni] = *(const f16x8*)&Bs[r * 32 + ((quad ^ ((r >> 1) & 3)) * 8)];
    }
#pragma unroll
    for (int mi = 0; mi < 4; mi++)
#pragma unroll
      for (int ni = 0; ni < 4; ni++)
        acc[mi][ni] = __builtin_amdgcn_mfma_f32_16x16x32_f16(
            af[mi], bfr[ni], acc[mi][ni], 0, 0, 0);
  }
  float bcol[4];
  if constexpr (HAS_BIAS) {
    const int isf = *FLAG;
#pragma unroll
    for (int ni = 0; ni < 4; ni++)
      bcol[ni] = ldi(biasBase, bOff + n0 + wn + ni * 16 + l15, isf);
  }
#pragma unroll
  for (int mi = 0; mi < 4; mi++) {
    int rowg = m0 + wm + mi * 16 + quad * 4;
#pragma unroll
    for (int ni = 0; ni < 4; ni++) {
      int colg = n0 + wn + ni * 16 + l15;
#pragma unroll
      for (int rr = 0; rr < 4; rr++) {
        long off = (long)(rowg + rr) * N + colg;
        float v = acc[mi][ni][rr];
        if constexpr (HAS_BIAS) v += bcol[ni];
        if constexpr (DO_RES) v += R[off];
        if constexpr (DO_GELU) v = gelu_f(v);
        if constexpr (OUT_H) ((_Float16*)Cout)[off] = (_Float16)v;
        else ((float*)Cout)[off] = v;
      }
    }
  }
}

// ---------------------------------------------------------------------------
// top-6 of MV[b,:] + softmax.  grid (32), block 256
// ---------------------------------------------------------------------------
__global__ __launch_bounds__(256) void topk_k(const float* __restrict__ MV,
                                              float* __restrict__ WGT,
                                              int* __restrict__ DLY) {
  int b = blockIdx.x;
  __shared__ float vals[LL];
  __shared__ float rv[256];
  __shared__ int ri[256];
  __shared__ float selv[6];
  int tid = threadIdx.x;
  for (int i = tid; i < LL; i += 256) vals[i] = MV[(long)b * LL + i];
  __syncthreads();
  for (int it = 0; it < 6; it++) {
    float bv = -1e30f;
    int bi = LL - 1;
    for (int i = tid; i < LL; i += 256) {
      float v = vals[i];
      if (v > bv || (v == bv && i < bi)) { bv = v; bi = i; }
    }
    rv[tid] = bv; ri[tid] = bi;
    __syncthreads();
    for (int st = 128; st > 0; st >>= 1) {
      if (tid < st) {
        float ov = rv[tid + st]; int oi = ri[tid + st];
        if (ov > rv[tid] || (ov == rv[tid] && oi < ri[tid])) {
          rv[tid] = ov; ri[tid] = oi;
        }
      }
      __syncthreads();
    }
    if (tid == 0) {
      selv[it] = rv[0];
      DLY[b * 6 + it] = ri[0];
      vals[ri[0]] = -1e30f;
    }
    __syncthreads();
  }
  if (tid == 0) {
    float mx = selv[0];
    float e[6], s = 0.0f;
    for (int i = 0; i < 6; i++) { e[i] = expf(selv[i] - mx); s += e[i]; }
    for (int i = 0; i < 6; i++) WGT[b * 6 + i] = e[i] / s;
  }
}

// ---------------------------------------------------------------------------
// time-delay aggregation, fp16 in/out (chunk-local): grid (1024, NB), block 128
// ---------------------------------------------------------------------------
__global__ __launch_bounds__(128) void agg_k(const _Float16* __restrict__ V,
                                             const float* __restrict__ WGT,
                                             const int* __restrict__ DLY,
                                             _Float16* __restrict__ O) {
  int l = blockIdx.x, b = blockIdx.y;
  int tid = threadIdx.x;
  float w[6]; int dl[6];
#pragma unroll
  for (int i = 0; i < 6; i++) { w[i] = WGT[b * 6 + i]; dl[i] = DLY[b * 6 + i]; }
  long base = (long)b * LL * DD;
  int d = tid * 4;
  float a0 = 0, a1 = 0, a2 = 0, a3 = 0;
#pragma unroll
  for (int i = 0; i < 6; i++) {
    int row = (l + dl[i]) & (LL - 1);
    H4 t; t.u = *(const uint2*)&V[base + (long)row * DD + d];
    a0 += w[i] * (float)t.h[0];
    a1 += w[i] * (float)t.h[1];
    a2 += w[i] * (float)t.h[2];
    a3 += w[i] * (float)t.h[3];
  }
  H4 r;
  r.h[0] = (_Float16)a0; r.h[1] = (_Float16)a1;
  r.h[2] = (_Float16)a2; r.h[3] = (_Float16)a3;
  *(uint2*)&O[base + (long)l * DD + d] = r.u;
}

// ---------------------------------------------------------------------------
// series_decomp residual. grid (2, 16, 32), block 256
// ---------------------------------------------------------------------------
__global__ __launch_bounds__(256) void decomp_k(const float* __restrict__ Xin,
                                                float* __restrict__ Out) {
  int d = blockIdx.x * 256 + threadIdx.x;
  int l0 = blockIdx.y * 64;
  int b = blockIdx.z;
  const float* xb = Xin + (long)b * LL * DD + d;
  float* ob = Out + (long)b * LL * DD + d;
  float wsum = 0.0f;
  for (int j = l0 - 12; j <= l0 + 12; j++) {
    int jj = min(max(j, 0), LL - 1);
    wsum += xb[(long)jj * DD];
  }
  for (int l = l0; l < l0 + 64; l++) {
    float xv = xb[(long)l * DD];
    ob[(long)l * DD] = xv - wsum * (1.0f / 25.0f);
    int ja = min(l + 13, LL - 1);
    int jr = max(l - 12, 0);
    wsum += xb[(long)ja * DD] - xb[(long)jr * DD];
  }
}

// special layernorm. grid (1024,32), block 256
__global__ __launch_bounds__(256) void ln_k(const float* __restrict__ X,
                                            const void* __restrict__ g,
                                            const void* __restrict__ be,
                                            float* __restrict__ XH,
                                            const int* __restrict__ FLAG) {
  const int isf = *FLAG;
  int l = blockIdx.x, b = blockIdx.y;
  const float* xr = X + ((long)b * LL + l) * DD;
  int tid = threadIdx.x;
  float x0 = xr[tid], x1 = xr[tid + 256];
  __shared__ float rs[256], rq[256];
  rs[tid] = x0 + x1;
  rq[tid] = x0 * x0 + x1 * x1;
  __syncthreads();
  for (int st = 128; st > 0; st >>= 1) {
    if (tid < st) { rs[tid] += rs[tid + st]; rq[tid] += rq[tid + st]; }
    __syncthreads();
  }
  float mu = rs[0] * (1.0f / 512.0f);
  float var = rq[0] * (1.0f / 512.0f) - mu * mu;
  float rstd = rsqrtf(var + 1e-5f);
  float* o = XH + ((long)b * LL + l) * DD;
  o[tid] = (x0 - mu) * rstd * ldi(g, tid, isf) + ldi(be, tid, isf);
  o[tid + 256] = (x1 - mu) * rstd * ldi(g, tid + 256, isf) + ldi(be, tid + 256, isf);
}

// colmean. grid (2,32), block 256
__global__ __launch_bounds__(256) void colmean_k(const float* __restrict__ XH,
                                                 float* __restrict__ CM) {
  int d = blockIdx.x * 256 + threadIdx.x;
  int b = blockIdx.y;
  const float* p = XH + (long)b * LL * DD + d;
  float s = 0.0f;
  for (int l = 0; l < LL; l++) s += p[(long)l * DD];
  CM[(long)b * DD + d] = s * (1.0f / 1024.0f);
}

// OUT = gelu(XH - CM) * mark. grid (1024,32), block 256
__global__ __launch_bounds__(256) void geluout_k(const float* __restrict__ XH,
                                                 const float* __restrict__ CM,
                                                 const void* __restrict__ mark,
                                                 float* __restrict__ OUT,
                                                 const int* __restrict__ FLAG) {
  const int isf = *FLAG;
  int l = blockIdx.x, b = blockIdx.y;
  int tid = threadIdx.x;
  float mk = ldi(mark, (long)b * LL + l, isf);
  long off = ((long)b * LL + l) * DD;
#pragma unroll
  for (int h = 0; h < 2; h++) {
    int d = tid + h * 256;
    float v = XH[off + d] - CM[(long)b * DD + d];
    OUT[off + d] = gelu_f(v) * mk;
  }
}

// proj stage 1. grid (16, 10, 32), block 256
__global__ __launch_bounds__(256) void proj1_k(const float* __restrict__ OUT,
                                               const void* __restrict__ Wp,
                                               float* __restrict__ PB,
                                               const int* __restrict__ FLAG) {
  const int isf = *FLAG;
  int chunk = blockIdx.x, n = blockIdx.y, b = blockIdx.z;
  long e0 = (long)chunk * 32768;
  const float* xb = OUT + (long)b * 524288 + e0;
  long wbase = (long)n * 524288 + e0;
  int tid = threadIdx.x;
  float s = 0.0f;
  if (isf) {
    const float* wr = (const float*)Wp + wbase;
    for (int i = tid * 4; i < 32768; i += 1024) {
      float4 x = *(const float4*)&xb[i];
      float4 w = *(const float4*)&wr[i];
      s += x.x * w.x + x.y * w.y + x.z * w.z + x.w * w.w;
    }
  } else {
    const u16* wr = (const u16*)Wp + wbase;
    for (int i = tid * 4; i < 32768; i += 1024) {
      float4 x = *(const float4*)&xb[i];
      uint2 u = *(const uint2*)&wr[i];
      s += x.x * bf2f((u16)(u.x & 0xffff)) + x.y * bf2f((u16)(u.x >> 16)) +
           x.z * bf2f((u16)(u.y & 0xffff)) + x.w * bf2f((u16)(u.y >> 16));
    }
  }
  __shared__ float red[256];
  red[tid] = s;
  __syncthreads();
  for (int st = 128; st > 0; st >>= 1) {
    if (tid < st) red[tid] += red[tid + st];
    __syncthreads();
  }
  if (tid == 0) PB[((long)b * 10 + n) * 16 + chunk] = red[0];
}

// proj stage 2: logits -> out (dtype per FLAG). grid (1), block 320
__global__ __launch_bounds__(320) void proj2_k(const float* __restrict__ PB,
                                               const void* __restrict__ bp,
                                               void* __restrict__ out,
                                               const int* __restrict__ FLAG) {
  const int isf = *FLAG;
  int id = threadIdx.x;
  int b = id / 10, n = id % 10;
  float s = ldi(bp, n, isf);
  for (int c = 0; c < 16; c++) s += PB[((long)b * 10 + n) * 16 + c];
  if (isf) ((float*)out)[b * 10 + n] = s;
  else ((u16*)out)[b * 10 + n] = f2bf(s);
}

// ---------------------------------------------------------------------------
extern "C" void kernel_launch(void* const* d_in, const int* in_sizes, int n_in,
                              void* d_out, int out_size, void* d_ws, size_t ws_size,
                              hipStream_t stream) {
  const void* xe = d_in[0];
  const void* mark = d_in[1];
  const void* cw = d_in[2];
  const void* Wq = d_in[3];
  const void* bq = d_in[4];
  const void* Wk = d_in[5];
  const void* bk = d_in[6];
  const void* Wv = d_in[7];
  const void* bv = d_in[8];
  const void* Wo = d_in[9];
  const void* bo = d_in[10];
  const void* Wff1 = d_in[11];
  const void* Wff2 = d_in[12];
  const void* lng = d_in[13];
  const void* lnb = d_in[14];
  const void* Wp = d_in[15];
  const void* bp = d_in[16];

  char* ws = (char*)d_ws;
  float* X        = (float*)(ws + 0L);            // 64 MiB
  float* S2       = (float*)(ws + 67108864L);     // 64 MiB phase-aliased
  float* QC32     = (float*)(ws + 67108864L);     // QK phase: f32 Q chunk 8Mi
  float* KC32     = (float*)(ws + 75497472L);     // QK phase: f32 K chunk 8Mi
  _Float16* Xh    = (_Float16*)(ws + 67108864L);  // attn phase: fp16 X, 32Mi
  _Float16* AGh   = (_Float16*)(ws + 100663296L); // attn phase: agg, 32Mi
  _Float16* Ph    = (_Float16*)(ws + 134217728L); // 8 MiB chunk scratch
  _Float16* WB    = (_Float16*)(ws + 142606336L); // fp16 weights
  float* MV  = (float*)(ws + 148897792L);
  float* WGT = (float*)(ws + 149028864L);
  int*   DLY = (int*)(ws + 149029888L);
  float* CM  = (float*)(ws + 149030912L);
  float* PB  = (float*)(ws + 149096448L);
  int*  FLAG = (int*)(ws + 149116928L);
  _Float16* Hb = (_Float16*)X;                    // FFN hidden chunk (X dead)

  const long AD = (long)LL * DD;   // 524288
  const int M = BB * LL;           // 32768
  _Float16* Wvh = WB + 0;
  _Float16* Woh = WB + 262144;
  _Float16* W1h = WB + 524288;
  _Float16* W2h = WB + 1572864;

  detect_k<<<1, 64, 0, stream>>>((const uint32_t*)mark, FLAG);
  conv_embed_k<<<dim3(64, 32), 256, 0, stream>>>(xe, cw, X, FLAG);

  for (int l = 0; l < 3; l++) {
    const long oW = (long)l * DD * DD;
    const long oB = (long)l * DD;
    const long oF = (long)l * DFF * DD;

    // ---- Phase A: delay selection, exact f32 (R4-verified path) ----
    hipMemsetAsync(MV, 0, (long)BB * LL * sizeof(float), stream);
    for (int cb = 0; cb < 8; cb++) {
      const float* xc = X + (long)cb * 4 * AD;
      gemm_f32b<<<dim3(4, 32), 256, 0, stream>>>(
          xc, Wq, oW, bq, oB, QC32, 4096, DD, DD, FLAG);
      gemm_f32b<<<dim3(4, 32), 256, 0, stream>>>(
          xc, Wk, oW, bk, oB, KC32, 4096, DD, DD, FLAG);
      qkmv_k<<<dim3(8, 8, 4), 256, 0, stream>>>(QC32, KC32, MV + (long)cb * 4 * LL);
    }
    topk_k<<<32, 256, 0, stream>>>(MV, WGT, DLY);

    // ---- Phase B: fp16 MFMA for V / agg / Wo / FFN ----
    wcvt_k<<<128, 256, 0, stream>>>(Wv, oW, Wvh, 262144, FLAG);
    wcvt_k<<<128, 256, 0, stream>>>(Wo, oW, Woh, 262144, FLAG);
    wcvt_k<<<512, 256, 0, stream>>>(Wff1, oF, W1h, 1048576, FLAG);
    wcvt_k<<<512, 256, 0, stream>>>(Wff2, oF, W2h, 1048576, FLAG);

    // X -> fp16 (overwrites QC32/KC32 region; they're dead after topk)
    acvt_k<<<8192, 256, 0, stream>>>(X, Xh, 16777216);

    // V (fp16) per 8-batch chunk -> Ph, aggregate -> AGh
    for (int cb = 0; cb < 4; cb++) {
      const _Float16* xh = Xh + (long)cb * 8 * AD;
      gemm_h<1 | 8><<<dim3(4, 64), 256, 0, stream>>>(
          xh, Wvh, bv, oB, nullptr, Ph, 8192, DD, DD, FLAG);
      agg_k<<<dim3(1024, 8), 128, 0, stream>>>(
          Ph, WGT + cb * 48, DLY + cb * 48, AGh + (long)cb * 8 * AD);
    }

    // X = X + AGh @ Wo^T + bo (full M, in-place residual)
    gemm_h<1 | 4><<<dim3(4, 256), 256, 0, stream>>>(
        AGh, Woh, bo, oB, X, X, M, DD, DD, FLAG);

    // x = decomp(X) -> S2 (Xh/AGh dead)
    decomp_k<<<dim3(2, 16, 32), 256, 0, stream>>>(X, S2);

    // FFN per 8-batch chunk: XD->fp16 Ph; hidden fp16 -> Hb (X region);
    // S2chunk = S2chunk + (gelu-hidden) @ W2^T
    for (int cb = 0; cb < 4; cb++) {
      float* xd = S2 + (long)cb * 8 * AD;
      acvt_k<<<2048, 256, 0, stream>>>(xd, Ph, 4194304);
      gemm_h<2 | 8><<<dim3(16, 64), 256, 0, stream>>>(
          Ph, W1h, nullptr, 0, nullptr, Hb, 8192, DFF, DD, FLAG);
      gemm_h<4><<<dim3(4, 64), 256, 0, stream>>>(
          Hb, W2h, nullptr, 0, xd, xd, 8192, DD, DFF, FLAG);
    }

    // x = decomp(S2) -> X (next layer input)
    decomp_k<<<dim3(2, 16, 32), 256, 0, stream>>>(S2, X);
  }

  // final special layernorm + gelu + mask + projection
  ln_k<<<dim3(1024, 32), 256, 0, stream>>>(X, lng, lnb, S2, FLAG);
  colmean_k<<<dim3(2, 32), 256, 0, stream>>>(S2, CM);
  geluout_k<<<dim3(1024, 32), 256, 0, stream>>>(S2, CM, mark, X, FLAG);
  proj1_k<<<dim3(16, 10, 32), 256, 0, stream>>>(X, Wp, PB, FLAG);
  proj2_k<<<1, 320, 0, stream>>>(PB, bp, d_out, FLAG);
}

// Round 8
// 4257.673 us; speedup vs baseline: 3.2603x; 1.7439x over previous
//
#include <hip/hip_runtime.h>
#include <cstdint>

// ---------------------------------------------------------------------------
// Autoformer forward — hybrid precision v2:
//   * delay selection via G-trick + fp16x2 split MFMA:
//       G' = Wk^T-style small f32 GEMM; Z = X@G and the Q.K^T wrapped-diagonal
//       reduce run as split fp16 MFMA (main + /512-scaled correction accs,
//       ~2^-22 relative noise, ~500x below the fp16 level that flipped top-k).
//       Biases drop out exactly (tau-independent shift; top-k and softmax
//       are shift-invariant under circular wrap).
//   * V / Wo / FFN on plain fp16 MFMA (R7-verified).
// Inputs f32 (runtime-detected from x_mark_enc; bf16 fallback kept).
//
// Workspace (bytes), total ~148.1 MB (< R7-proven 149.1 MB):
//   X    @ 0          : [32,1024,512] f32 residual; FFN: Hb fp16 hidden
//   XH   @ 67108864   : fp16 X-high (32Mi)        [A: split, B: V-proj]
//   XL   @ 100663296  : fp16 X-low*512 (32Mi)     [A] / AGh (32Mi) [B]
//   ZH   @ 134217728  : fp16 Z-high chunk 4Mi     [A] \ Ph 8Mi (V/XDh chunk) [B]
//   ZL   @ 138412032  : fp16 Z-low*512 chunk 4Mi  [A] /
//   SH   @ 142606336  : 5.25Mi shared: Phase A: G32(1Mi)+GH(.5)+GL(.5)
//                       Phase B: Wvh(.5)+Woh(.5)+W1h(2)+W2h(2)
//   MV   @ 147849216  : [32,1024] f32
//   WGT  @ 147980288, DLY @ 147981312, CM @ 147982336, PB @ 148047872,
//   FLAG @ 148068352
//   FFN phase: XD f32 full 64Mi @ 67108864 (over XH+XL, dead then)
// ---------------------------------------------------------------------------

using u16 = unsigned short;
typedef _Float16 f16x8 __attribute__((ext_vector_type(8)));
typedef float f32x4 __attribute__((ext_vector_type(4)));

#define BB 32
#define LL 1024
#define DD 512
#define DFF 2048

__device__ __forceinline__ float bf2f(u16 u) {
  union { uint32_t i; float f; } v; v.i = ((uint32_t)u) << 16; return v.f;
}
__device__ __forceinline__ u16 f2bf(float f) {
  union { float f; uint32_t i; } v; v.f = f;
  uint32_t r = (v.i + 0x7FFFu + ((v.i >> 16) & 1u)) >> 16;
  return (u16)r;
}
__device__ __forceinline__ float ldi(const void* p, long i, int isf) {
  return isf ? ((const float*)p)[i] : bf2f(((const u16*)p)[i]);
}
__device__ __forceinline__ float gelu_f(float x) {
  return 0.5f * x * (1.0f + erff(x * 0.70710678118654752440f));
}

union H8 { f16x8 v; uint4 u; _Float16 h[8]; };
union H4 { uint2 u; _Float16 h[4]; };

__global__ void detect_k(const uint32_t* __restrict__ mark, int* __restrict__ FLAG) {
  if (threadIdx.x == 0) FLAG[0] = (mark[0] == 0x3F800000u) ? 1 : 0;
}

// ---------------------------------------------------------------------------
// Conv1d circular embedding. grid (L/16, B), block 256
// ---------------------------------------------------------------------------
__global__ __launch_bounds__(256) void conv_embed_k(
    const void* __restrict__ xe, const void* __restrict__ w,
    float* __restrict__ X, const int* __restrict__ FLAG) {
  const int isf = *FLAG;
  int b = blockIdx.y;
  int l0 = blockIdx.x * 16;
  __shared__ float xs[18][21];
  int tid = threadIdx.x;
  for (int i = tid; i < 18 * 21; i += 256) {
    int r = i / 21, c = i % 21;
    int row = (l0 - 1 + r + LL) & (LL - 1);
    xs[r][c] = ldi(xe, ((long)b * LL + row) * 21 + c, isf);
  }
  __syncthreads();
  for (int d = tid; d < DD; d += 256) {
    float acc[16];
#pragma unroll
    for (int ll = 0; ll < 16; ll++) acc[ll] = 0.0f;
    for (int c = 0; c < 21; c++) {
#pragma unroll
      for (int t = 0; t < 3; t++) {
        float wv = ldi(w, (long)d * 63 + c * 3 + t, isf);
#pragma unroll
        for (int ll = 0; ll < 16; ll++) acc[ll] += wv * xs[t + ll][c];
      }
    }
    for (int ll = 0; ll < 16; ll++)
      X[((long)b * LL + l0 + ll) * DD + d] = acc[ll];
  }
}

// ---------------------------------------------------------------------------
// G'[r,c] = sum_f W1[f,r] * W2[f,c]   (f32, transposed-read small GEMM)
// call with (Wk, Wq): G'[d,e] = sum_f Wk[f,d] Wq[f,e]  so that
// Z[m,d] = sum_e X[m,e] * G'[d,e] equals (X Wq^T)·(row d of Wk) contraction.
// grid (8,8), block 256 (16x16, 4x4 outputs/thread)
// ---------------------------------------------------------------------------
__global__ __launch_bounds__(256) void gt_k(
    const void* __restrict__ W1, const void* __restrict__ W2, long off,
    float* __restrict__ G, const int* __restrict__ FLAG) {
  const int isf = *FLAG;
  __shared__ float A1[64][65];
  __shared__ float A2[64][65];
  int c0 = blockIdx.x * 64, r0 = blockIdx.y * 64;
  int tid = threadIdx.x;
  int tx = tid & 15, ty = tid >> 4;
  float acc[4][4] = {};
  for (int f0 = 0; f0 < DD; f0 += 64) {
    for (int i = tid; i < 64 * 64; i += 256) {
      int r = i >> 6, c = i & 63;
      A1[r][c] = ldi(W1, off + (long)(f0 + r) * DD + r0 + c, isf);
      A2[r][c] = ldi(W2, off + (long)(f0 + r) * DD + c0 + c, isf);
    }
    __syncthreads();
    for (int f = 0; f < 64; f++) {
      float av[4], bv[4];
#pragma unroll
      for (int i = 0; i < 4; i++) av[i] = A1[f][ty * 4 + i];
#pragma unroll
      for (int j = 0; j < 4; j++) bv[j] = A2[f][tx * 4 + j];
#pragma unroll
      for (int i = 0; i < 4; i++)
#pragma unroll
        for (int j = 0; j < 4; j++) acc[i][j] = fmaf(av[i], bv[j], acc[i][j]);
    }
    __syncthreads();
  }
#pragma unroll
  for (int i = 0; i < 4; i++)
#pragma unroll
    for (int j = 0; j < 4; j++)
      G[(long)(r0 + ty * 4 + i) * DD + c0 + tx * 4 + j] = acc[i][j];
}

// ---------------------------------------------------------------------------
// split f32 -> (fp16 high, fp16 low*512). 8 elems/thread.
// ---------------------------------------------------------------------------
__global__ __launch_bounds__(256) void split_k(const float* __restrict__ src,
                                               _Float16* __restrict__ dh,
                                               _Float16* __restrict__ dl, int n) {
  long i = ((long)blockIdx.x * 256 + threadIdx.x) * 8;
  if (i >= n) return;
  float4 a = *(const float4*)(src + i);
  float4 b = *(const float4*)(src + i + 4);
  float x[8] = {a.x, a.y, a.z, a.w, b.x, b.y, b.z, b.w};
  H8 h, l;
#pragma unroll
  for (int j = 0; j < 8; j++) {
    _Float16 hv = (_Float16)x[j];
    h.h[j] = hv;
    l.h[j] = (_Float16)((x[j] - (float)hv) * 512.0f);
  }
  *(uint4*)(dh + i) = h.u;
  *(uint4*)(dl + i) = l.u;
}

// convert f32 -> fp16 (plain), 8 elems/thread
__global__ __launch_bounds__(256) void acvt_k(const float* __restrict__ src,
                                              _Float16* __restrict__ dst, int n) {
  long i = ((long)blockIdx.x * 256 + threadIdx.x) * 8;
  if (i >= n) return;
  float4 a = *(const float4*)(src + i);
  float4 b = *(const float4*)(src + i + 4);
  H8 r;
  r.h[0] = (_Float16)a.x; r.h[1] = (_Float16)a.y;
  r.h[2] = (_Float16)a.z; r.h[3] = (_Float16)a.w;
  r.h[4] = (_Float16)b.x; r.h[5] = (_Float16)b.y;
  r.h[6] = (_Float16)b.z; r.h[7] = (_Float16)b.w;
  *(uint4*)(dst + i) = r.u;
}

// convert external weight (f32 or bf16 per FLAG) -> fp16
__global__ __launch_bounds__(256) void wcvt_k(const void* __restrict__ src, long off,
                                              _Float16* __restrict__ dst, int n,
                                              const int* __restrict__ FLAG) {
  const int isf = *FLAG;
  long i = ((long)blockIdx.x * 256 + threadIdx.x) * 8;
  if (i >= n) return;
  H8 r;
  if (isf) {
    const float* s = (const float*)src + off + i;
    float4 a = *(const float4*)s;
    float4 b = *(const float4*)(s + 4);
    r.h[0] = (_Float16)a.x; r.h[1] = (_Float16)a.y;
    r.h[2] = (_Float16)a.z; r.h[3] = (_Float16)a.w;
    r.h[4] = (_Float16)b.x; r.h[5] = (_Float16)b.y;
    r.h[6] = (_Float16)b.z; r.h[7] = (_Float16)b.w;
  } else {
    const u16* s = (const u16*)src + off + i;
    uint4 u = *(const uint4*)s;
    r.h[0] = (_Float16)bf2f((u16)(u.x & 0xffff));
    r.h[1] = (_Float16)bf2f((u16)(u.x >> 16));
    r.h[2] = (_Float16)bf2f((u16)(u.y & 0xffff));
    r.h[3] = (_Float16)bf2f((u16)(u.y >> 16));
    r.h[4] = (_Float16)bf2f((u16)(u.z & 0xffff));
    r.h[5] = (_Float16)bf2f((u16)(u.z >> 16));
    r.h[6] = (_Float16)bf2f((u16)(u.w & 0xffff));
    r.h[7] = (_Float16)bf2f((u16)(u.w >> 16));
  }
  *(uint4*)(dst + i) = r.u;
}

// ---------------------------------------------------------------------------
// split-fp16 MFMA GEMM: Z = A @ W^T where A=(Ah+Al/512), W=(Bh+Bl/512).
// acc_main = Ah.Bh ; acc_corr = Ah.Bl + Al.Bh ; z = main + corr/512.
// Writes split (Zh, Zl*512) fp16.  tile 128x128, BK=32, 256 thr.
// ---------------------------------------------------------------------------
__global__ __launch_bounds__(256) void gemm_z(
    const _Float16* __restrict__ Ah, const _Float16* __restrict__ Al,
    const _Float16* __restrict__ Bh, const _Float16* __restrict__ Bl,
    _Float16* __restrict__ Zh, _Float16* __restrict__ Zl,
    int M, int N, int K) {
  __shared__ __align__(16) _Float16 AsH[128 * 32];
  __shared__ __align__(16) _Float16 AsL[128 * 32];
  __shared__ __align__(16) _Float16 BsH[128 * 32];
  __shared__ __align__(16) _Float16 BsL[128 * 32];
  const int n0 = blockIdx.x * 128, m0 = blockIdx.y * 128;
  const int tid = threadIdx.x;
  const int lane = tid & 63, wvi = tid >> 6;
  const int wm = (wvi >> 1) * 64, wn = (wvi & 1) * 64;
  const int l15 = lane & 15, quad = lane >> 4;
  const int srow = tid >> 1;
  const int sseg = (tid & 1) * 2;
  const int sg = (srow >> 1) & 3;
  const int wo1 = srow * 32 + ((sseg ^ sg) * 8);
  const int wo2 = srow * 32 + (((sseg + 1) ^ sg) * 8);
  const long aoff = (long)(m0 + srow) * K + sseg * 8;
  const long boff = (long)(n0 + srow) * K + sseg * 8;
  f32x4 aM[4][4], aC[4][4];
#pragma unroll
  for (int i = 0; i < 4; i++)
#pragma unroll
    for (int j = 0; j < 4; j++) {
      aM[i][j] = (f32x4){0.f, 0.f, 0.f, 0.f};
      aC[i][j] = (f32x4){0.f, 0.f, 0.f, 0.f};
    }
  for (int k0 = 0; k0 < K; k0 += 32) {
    uint4 ah1 = *(const uint4*)(Ah + aoff + k0);
    uint4 ah2 = *(const uint4*)(Ah + aoff + k0 + 8);
    uint4 al1 = *(const uint4*)(Al + aoff + k0);
    uint4 al2 = *(const uint4*)(Al + aoff + k0 + 8);
    uint4 bh1 = *(const uint4*)(Bh + boff + k0);
    uint4 bh2 = *(const uint4*)(Bh + boff + k0 + 8);
    uint4 bl1 = *(const uint4*)(Bl + boff + k0);
    uint4 bl2 = *(const uint4*)(Bl + boff + k0 + 8);
    __syncthreads();
    *(uint4*)&AsH[wo1] = ah1; *(uint4*)&AsH[wo2] = ah2;
    *(uint4*)&AsL[wo1] = al1; *(uint4*)&AsL[wo2] = al2;
    *(uint4*)&BsH[wo1] = bh1; *(uint4*)&BsH[wo2] = bh2;
    *(uint4*)&BsL[wo1] = bl1; *(uint4*)&BsL[wo2] = bl2;
    __syncthreads();
    f16x8 fah[4], fal[4], fbh[4], fbl[4];
#pragma unroll
    for (int mi = 0; mi < 4; mi++) {
      int r = wm + mi * 16 + l15;
      int o = r * 32 + ((quad ^ ((r >> 1) & 3)) * 8);
      fah[mi] = *(const f16x8*)&AsH[o];
      fal[mi] = *(const f16x8*)&AsL[o];
    }
#pragma unroll
    for (int ni = 0; ni < 4; ni++) {
      int r = wn + ni * 16 + l15;
      int o = r * 32 + ((quad ^ ((r >> 1) & 3)) * 8);
      fbh[ni] = *(const f16x8*)&BsH[o];
      fbl[ni] = *(const f16x8*)&BsL[o];
    }
#pragma unroll
    for (int mi = 0; mi < 4; mi++)
#pragma unroll
      for (int ni = 0; ni < 4; ni++) {
        aM[mi][ni] = __builtin_amdgcn_mfma_f32_16x16x32_f16(
            fah[mi], fbh[ni], aM[mi][ni], 0, 0, 0);
        aC[mi][ni] = __builtin_amdgcn_mfma_f32_16x16x32_f16(
            fah[mi], fbl[ni], aC[mi][ni], 0, 0, 0);
        aC[mi][ni] = __builtin_amdgcn_mfma_f32_16x16x32_f16(
            fal[mi], fbh[ni], aC[mi][ni], 0, 0, 0);
      }
  }
#pragma unroll
  for (int mi = 0; mi < 4; mi++) {
    int rowg = m0 + wm + mi * 16 + quad * 4;
#pragma unroll
    for (int ni = 0; ni < 4; ni++) {
      int colg = n0 + wn + ni * 16 + l15;
#pragma unroll
      for (int rr = 0; rr < 4; rr++) {
        long off = (long)(rowg + rr) * N + colg;
        float z = aM[mi][ni][rr] + aC[mi][ni][rr] * (1.0f / 512.0f);
        _Float16 zh = (_Float16)z;
        Zh[off] = zh;
        Zl[off] = (_Float16)((z - (float)zh) * 512.0f);
      }
    }
  }
}

// ---------------------------------------------------------------------------
// split-fp16 MFMA Z.X^T with fused wrapped-diagonal mean reduction:
//   MV[b,tau] += (1/512) * sum_t Z[b,(t+tau)%L,:] . X[b,t,:]
// grid (8, 8, NB), block 256.  MV (chunk-offset) zeroed beforehand.
// ---------------------------------------------------------------------------
__global__ __launch_bounds__(256) void qkmv_hl(
    const _Float16* __restrict__ Zh, const _Float16* __restrict__ Zl,
    const _Float16* __restrict__ Xh, const _Float16* __restrict__ Xl,
    float* __restrict__ MV) {
  __shared__ __align__(16) _Float16 AsH[128 * 32];
  __shared__ __align__(16) _Float16 AsL[128 * 32];
  __shared__ __align__(16) _Float16 BsH[128 * 32];
  __shared__ __align__(16) _Float16 BsL[128 * 32];
  __shared__ float diag[255];
  const int bz = blockIdx.z;
  const long bb = (long)bz * LL * DD;
  const int n0 = blockIdx.x * 128, m0 = blockIdx.y * 128;
  const int tid = threadIdx.x;
  const int lane = tid & 63, wvi = tid >> 6;
  const int wm = (wvi >> 1) * 64, wn = (wvi & 1) * 64;
  const int l15 = lane & 15, quad = lane >> 4;
  const int srow = tid >> 1;
  const int sseg = (tid & 1) * 2;
  const int sg = (srow >> 1) & 3;
  const int wo1 = srow * 32 + ((sseg ^ sg) * 8);
  const int wo2 = srow * 32 + (((sseg + 1) ^ sg) * 8);
  const long aoff = bb + (long)(m0 + srow) * DD + sseg * 8;
  const long boff = bb + (long)(n0 + srow) * DD + sseg * 8;
  if (tid < 255) diag[tid] = 0.0f;
  f32x4 aM[4][4], aC[4][4];
#pragma unroll
  for (int i = 0; i < 4; i++)
#pragma unroll
    for (int j = 0; j < 4; j++) {
      aM[i][j] = (f32x4){0.f, 0.f, 0.f, 0.f};
      aC[i][j] = (f32x4){0.f, 0.f, 0.f, 0.f};
    }
  for (int k0 = 0; k0 < DD; k0 += 32) {
    uint4 ah1 = *(const uint4*)(Zh + aoff + k0);
    uint4 ah2 = *(const uint4*)(Zh + aoff + k0 + 8);
    uint4 al1 = *(const uint4*)(Zl + aoff + k0);
    uint4 al2 = *(const uint4*)(Zl + aoff + k0 + 8);
    uint4 bh1 = *(const uint4*)(Xh + boff + k0);
    uint4 bh2 = *(const uint4*)(Xh + boff + k0 + 8);
    uint4 bl1 = *(const uint4*)(Xl + boff + k0);
    uint4 bl2 = *(const uint4*)(Xl + boff + k0 + 8);
    __syncthreads();
    *(uint4*)&AsH[wo1] = ah1; *(uint4*)&AsH[wo2] = ah2;
    *(uint4*)&AsL[wo1] = al1; *(uint4*)&AsL[wo2] = al2;
    *(uint4*)&BsH[wo1] = bh1; *(uint4*)&BsH[wo2] = bh2;
    *(uint4*)&BsL[wo1] = bl1; *(uint4*)&BsL[wo2] = bl2;
    __syncthreads();
    f16x8 fah[4], fal[4], fbh[4], fbl[4];
#pragma unroll
    for (int mi = 0; mi < 4; mi++) {
      int r = wm + mi * 16 + l15;
      int o = r * 32 + ((quad ^ ((r >> 1) & 3)) * 8);
      fah[mi] = *(const f16x8*)&AsH[o];
      fal[mi] = *(const f16x8*)&AsL[o];
    }
#pragma unroll
    for (int ni = 0; ni < 4; ni++) {
      int r = wn + ni * 16 + l15;
      int o = r * 32 + ((quad ^ ((r >> 1) & 3)) * 8);
      fbh[ni] = *(const f16x8*)&BsH[o];
      fbl[ni] = *(const f16x8*)&BsL[o];
    }
#pragma unroll
    for (int mi = 0; mi < 4; mi++)
#pragma unroll
      for (int ni = 0; ni < 4; ni++) {
        aM[mi][ni] = __builtin_amdgcn_mfma_f32_16x16x32_f16(
            fah[mi], fbh[ni], aM[mi][ni], 0, 0, 0);
        aC[mi][ni] = __builtin_amdgcn_mfma_f32_16x16x32_f16(
            fah[mi], fbl[ni], aC[mi][ni], 0, 0, 0);
        aC[mi][ni] = __builtin_amdgcn_mfma_f32_16x16x32_f16(
            fal[mi], fbh[ni], aC[mi][ni], 0, 0, 0);
      }
  }
  // element (m,n): m = wm+mi*16+quad*4+rr, n = wn+ni*16+l15; dl = m-n
#pragma unroll
  for (int g = -3; g <= 3; g++) {
#pragma unroll
    for (int rr = 0; rr < 4; rr++) {
      float s = 0.0f;
#pragma unroll
      for (int mi = 0; mi < 4; mi++) {
        int ni = mi - g;
        if (ni >= 0 && ni < 4)
          s += aM[mi][ni][rr] + aC[mi][ni][rr] * (1.0f / 512.0f);
      }
      int d = 127 + (wm - wn) + g * 16 + quad * 4 + rr - l15;
      atomicAdd(&diag[d], s);
    }
  }
  __syncthreads();
  if (tid < 255) {
    int tau = (m0 - n0 + tid - 127 + LL) & (LL - 1);
    atomicAdd(&MV[(long)bz * LL + tau], diag[tid] * (1.0f / 512.0f));
  }
}

// ---------------------------------------------------------------------------
// fp16 MFMA GEMM: C[M,N] = act( A[M,K] @ W[N,K]^T + bias + R )
// FLAGS: 1=bias 2=gelu 4=residual 8=out-fp16 (R7-verified)
// ---------------------------------------------------------------------------
template <int FLAGS>
__global__ __launch_bounds__(256) void gemm_h(
    const _Float16* __restrict__ A, const _Float16* __restrict__ W,
    const void* __restrict__ biasBase, long bOff,
    const float* __restrict__ R, void* __restrict__ Cout,
    int M, int N, int K, const int* __restrict__ FLAG) {
  constexpr bool HAS_BIAS = (FLAGS & 1) != 0;
  constexpr bool DO_GELU = (FLAGS & 2) != 0;
  constexpr bool DO_RES = (FLAGS & 4) != 0;
  constexpr bool OUT_H = (FLAGS & 8) != 0;
  __shared__ __align__(16) _Float16 As[128 * 32];
  __shared__ __align__(16) _Float16 Bs[128 * 32];
  const int n0 = blockIdx.x * 128, m0 = blockIdx.y * 128;
  const int tid = threadIdx.x;
  const int lane = tid & 63, wvi = tid >> 6;
  const int wm = (wvi >> 1) * 64, wn = (wvi & 1) * 64;
  const int l15 = lane & 15, quad = lane >> 4;
  const int srow = tid >> 1;
  const int sseg = (tid & 1) * 2;
  const int sg = (srow >> 1) & 3;
  const int wo1 = srow * 32 + ((sseg ^ sg) * 8);
  const int wo2 = srow * 32 + (((sseg + 1) ^ sg) * 8);
  const _Float16* aptr = A + (long)(m0 + srow) * K + sseg * 8;
  const _Float16* wptr = W + (long)(n0 + srow) * K + sseg * 8;
  f32x4 acc[4][4];
#pragma unroll
  for (int i = 0; i < 4; i++)
#pragma unroll
    for (int j = 0; j < 4; j++) acc[i][j] = (f32x4){0.f, 0.f, 0.f, 0.f};
  for (int k0 = 0; k0 < K; k0 += 32) {
    uint4 av1 = *(const uint4*)(aptr + k0);
    uint4 av2 = *(const uint4*)(aptr + k0 + 8);
    uint4 wv1 = *(const uint4*)(wptr + k0);
    uint4 wv2 = *(const uint4*)(wptr + k0 + 8);
    __syncthreads();
    *(uint4*)&As[wo1] = av1; *(uint4*)&As[wo2] = av2;
    *(uint4*)&Bs[wo1] = wv1; *(uint4*)&Bs[wo2] = wv2;
    __syncthreads();
    f16x8 af[4], bfr[4];
#pragma unroll
    for (int mi = 0; mi < 4; mi++) {
      int r = wm + mi * 16 + l15;
      af[mi] = *(const f16x8*)&As[r * 32 + ((quad ^ ((r >> 1) & 3)) * 8)];
    }
#pragma unroll
    for (int ni = 0; ni < 4; ni++) {
      int r = wn + ni * 16 + l15;
      bfr[ni] = *(const f16x8*)&Bs[r * 32 + ((quad ^ ((r >> 1) & 3)) * 8)];
    }
#pragma unroll
    for (int mi = 0; mi < 4; mi++)
#pragma unroll
      for (int ni = 0; ni < 4; ni++)
        acc[mi][ni] = __builtin_amdgcn_mfma_f32_16x16x32_f16(
            af[mi], bfr[ni], acc[mi][ni], 0, 0, 0);
  }
  float bcol[4];
  if constexpr (HAS_BIAS) {
    const int isf = *FLAG;
#pragma unroll
    for (int ni = 0; ni < 4; ni++)
      bcol[ni] = ldi(biasBase, bOff + n0 + wn + ni * 16 + l15, isf);
  }
#pragma unroll
  for (int mi = 0; mi < 4; mi++) {
    int rowg = m0 + wm + mi * 16 + quad * 4;
#pragma unroll
    for (int ni = 0; ni < 4; ni++) {
      int colg = n0 + wn + ni * 16 + l15;
#pragma unroll
      for (int rr = 0; rr < 4; rr++) {
        long off = (long)(rowg + rr) * N + colg;
        float v = acc[mi][ni][rr];
        if constexpr (HAS_BIAS) v += bcol[ni];
        if constexpr (DO_RES) v += R[off];
        if constexpr (DO_GELU) v = gelu_f(v);
        if constexpr (OUT_H) ((_Float16*)Cout)[off] = (_Float16)v;
        else ((float*)Cout)[off] = v;
      }
    }
  }
}

// ---------------------------------------------------------------------------
// top-6 of MV[b,:] + softmax.  grid (32), block 256
// ---------------------------------------------------------------------------
__global__ __launch_bounds__(256) void topk_k(const float* __restrict__ MV,
                                              float* __restrict__ WGT,
                                              int* __restrict__ DLY) {
  int b = blockIdx.x;
  __shared__ float vals[LL];
  __shared__ float rv[256];
  __shared__ int ri[256];
  __shared__ float selv[6];
  int tid = threadIdx.x;
  for (int i = tid; i < LL; i += 256) vals[i] = MV[(long)b * LL + i];
  __syncthreads();
  for (int it = 0; it < 6; it++) {
    float bv = -1e30f;
    int bi = LL - 1;
    for (int i = tid; i < LL; i += 256) {
      float v = vals[i];
      if (v > bv || (v == bv && i < bi)) { bv = v; bi = i; }
    }
    rv[tid] = bv; ri[tid] = bi;
    __syncthreads();
    for (int st = 128; st > 0; st >>= 1) {
      if (tid < st) {
        float ov = rv[tid + st]; int oi = ri[tid + st];
        if (ov > rv[tid] || (ov == rv[tid] && oi < ri[tid])) {
          rv[tid] = ov; ri[tid] = oi;
        }
      }
      __syncthreads();
    }
    if (tid == 0) {
      selv[it] = rv[0];
      DLY[b * 6 + it] = ri[0];
      vals[ri[0]] = -1e30f;
    }
    __syncthreads();
  }
  if (tid == 0) {
    float mx = selv[0];
    float e[6], s = 0.0f;
    for (int i = 0; i < 6; i++) { e[i] = expf(selv[i] - mx); s += e[i]; }
    for (int i = 0; i < 6; i++) WGT[b * 6 + i] = e[i] / s;
  }
}

// ---------------------------------------------------------------------------
// time-delay aggregation, fp16 in/out (chunk-local): grid (1024, NB), block 128
// ---------------------------------------------------------------------------
__global__ __launch_bounds__(128) void agg_k(const _Float16* __restrict__ V,
                                             const float* __restrict__ WGT,
                                             const int* __restrict__ DLY,
                                             _Float16* __restrict__ O) {
  int l = blockIdx.x, b = blockIdx.y;
  int tid = threadIdx.x;
  float w[6]; int dl[6];
#pragma unroll
  for (int i = 0; i < 6; i++) { w[i] = WGT[b * 6 + i]; dl[i] = DLY[b * 6 + i]; }
  long base = (long)b * LL * DD;
  int d = tid * 4;
  float a0 = 0, a1 = 0, a2 = 0, a3 = 0;
#pragma unroll
  for (int i = 0; i < 6; i++) {
    int row = (l + dl[i]) & (LL - 1);
    H4 t; t.u = *(const uint2*)&V[base + (long)row * DD + d];
    a0 += w[i] * (float)t.h[0];
    a1 += w[i] * (float)t.h[1];
    a2 += w[i] * (float)t.h[2];
    a3 += w[i] * (float)t.h[3];
  }
  H4 r;
  r.h[0] = (_Float16)a0; r.h[1] = (_Float16)a1;
  r.h[2] = (_Float16)a2; r.h[3] = (_Float16)a3;
  *(uint2*)&O[base + (long)l * DD + d] = r.u;
}

// ---------------------------------------------------------------------------
// series_decomp residual. grid (2, 16, 32), block 256
// ---------------------------------------------------------------------------
__global__ __launch_bounds__(256) void decomp_k(const float* __restrict__ Xin,
                                                float* __restrict__ Out) {
  int d = blockIdx.x * 256 + threadIdx.x;
  int l0 = blockIdx.y * 64;
  int b = blockIdx.z;
  const float* xb = Xin + (long)b * LL * DD + d;
  float* ob = Out + (long)b * LL * DD + d;
  float wsum = 0.0f;
  for (int j = l0 - 12; j <= l0 + 12; j++) {
    int jj = min(max(j, 0), LL - 1);
    wsum += xb[(long)jj * DD];
  }
  for (int l = l0; l < l0 + 64; l++) {
    float xv = xb[(long)l * DD];
    ob[(long)l * DD] = xv - wsum * (1.0f / 25.0f);
    int ja = min(l + 13, LL - 1);
    int jr = max(l - 12, 0);
    wsum += xb[(long)ja * DD] - xb[(long)jr * DD];
  }
}

// special layernorm. grid (1024,32), block 256
__global__ __launch_bounds__(256) void ln_k(const float* __restrict__ X,
                                            const void* __restrict__ g,
                                            const void* __restrict__ be,
                                            float* __restrict__ XH,
                                            const int* __restrict__ FLAG) {
  const int isf = *FLAG;
  int l = blockIdx.x, b = blockIdx.y;
  const float* xr = X + ((long)b * LL + l) * DD;
  int tid = threadIdx.x;
  float x0 = xr[tid], x1 = xr[tid + 256];
  __shared__ float rs[256], rq[256];
  rs[tid] = x0 + x1;
  rq[tid] = x0 * x0 + x1 * x1;
  __syncthreads();
  for (int st = 128; st > 0; st >>= 1) {
    if (tid < st) { rs[tid] += rs[tid + st]; rq[tid] += rq[tid + st]; }
    __syncthreads();
  }
  float mu = rs[0] * (1.0f / 512.0f);
  float var = rq[0] * (1.0f / 512.0f) - mu * mu;
  float rstd = rsqrtf(var + 1e-5f);
  float* o = XH + ((long)b * LL + l) * DD;
  o[tid] = (x0 - mu) * rstd * ldi(g, tid, isf) + ldi(be, tid, isf);
  o[tid + 256] = (x1 - mu) * rstd * ldi(g, tid + 256, isf) + ldi(be, tid + 256, isf);
}

// colmean. grid (2,32), block 256
__global__ __launch_bounds__(256) void colmean_k(const float* __restrict__ XH,
                                                 float* __restrict__ CM) {
  int d = blockIdx.x * 256 + threadIdx.x;
  int b = blockIdx.y;
  const float* p = XH + (long)b * LL * DD + d;
  float s = 0.0f;
  for (int l = 0; l < LL; l++) s += p[(long)l * DD];
  CM[(long)b * DD + d] = s * (1.0f / 1024.0f);
}

// OUT = gelu(XH - CM) * mark. grid (1024,32), block 256
__global__ __launch_bounds__(256) void geluout_k(const float* __restrict__ XH,
                                                 const float* __restrict__ CM,
                                                 const void* __restrict__ mark,
                                                 float* __restrict__ OUT,
                                                 const int* __restrict__ FLAG) {
  const int isf = *FLAG;
  int l = blockIdx.x, b = blockIdx.y;
  int tid = threadIdx.x;
  float mk = ldi(mark, (long)b * LL + l, isf);
  long off = ((long)b * LL + l) * DD;
#pragma unroll
  for (int h = 0; h < 2; h++) {
    int d = tid + h * 256;
    float v = XH[off + d] - CM[(long)b * DD + d];
    OUT[off + d] = gelu_f(v) * mk;
  }
}

// proj stage 1. grid (16, 10, 32), block 256
__global__ __launch_bounds__(256) void proj1_k(const float* __restrict__ OUT,
                                               const void* __restrict__ Wp,
                                               float* __restrict__ PB,
                                               const int* __restrict__ FLAG) {
  const int isf = *FLAG;
  int chunk = blockIdx.x, n = blockIdx.y, b = blockIdx.z;
  long e0 = (long)chunk * 32768;
  const float* xb = OUT + (long)b * 524288 + e0;
  long wbase = (long)n * 524288 + e0;
  int tid = threadIdx.x;
  float s = 0.0f;
  if (isf) {
    const float* wr = (const float*)Wp + wbase;
    for (int i = tid * 4; i < 32768; i += 1024) {
      float4 x = *(const float4*)&xb[i];
      float4 w = *(const float4*)&wr[i];
      s += x.x * w.x + x.y * w.y + x.z * w.z + x.w * w.w;
    }
  } else {
    const u16* wr = (const u16*)Wp + wbase;
    for (int i = tid * 4; i < 32768; i += 1024) {
      float4 x = *(const float4*)&xb[i];
      uint2 u = *(const uint2*)&wr[i];
      s += x.x * bf2f((u16)(u.x & 0xffff)) + x.y * bf2f((u16)(u.x >> 16)) +
           x.z * bf2f((u16)(u.y & 0xffff)) + x.w * bf2f((u16)(u.y >> 16));
    }
  }
  __shared__ float red[256];
  red[tid] = s;
  __syncthreads();
  for (int st = 128; st > 0; st >>= 1) {
    if (tid < st) red[tid] += red[tid + st];
    __syncthreads();
  }
  if (tid == 0) PB[((long)b * 10 + n) * 16 + chunk] = red[0];
}

// proj stage 2: logits -> out (dtype per FLAG). grid (1), block 320
__global__ __launch_bounds__(320) void proj2_k(const float* __restrict__ PB,
                                               const void* __restrict__ bp,
                                               void* __restrict__ out,
                                               const int* __restrict__ FLAG) {
  const int isf = *FLAG;
  int id = threadIdx.x;
  int b = id / 10, n = id % 10;
  float s = ldi(bp, n, isf);
  for (int c = 0; c < 16; c++) s += PB[((long)b * 10 + n) * 16 + c];
  if (isf) ((float*)out)[b * 10 + n] = s;
  else ((u16*)out)[b * 10 + n] = f2bf(s);
}

// ---------------------------------------------------------------------------
extern "C" void kernel_launch(void* const* d_in, const int* in_sizes, int n_in,
                              void* d_out, int out_size, void* d_ws, size_t ws_size,
                              hipStream_t stream) {
  const void* xe = d_in[0];
  const void* mark = d_in[1];
  const void* cw = d_in[2];
  const void* Wq = d_in[3];
  const void* Wk = d_in[5];
  const void* Wv = d_in[7];
  const void* bv = d_in[8];
  const void* Wo = d_in[9];
  const void* bo = d_in[10];
  const void* Wff1 = d_in[11];
  const void* Wff2 = d_in[12];
  const void* lng = d_in[13];
  const void* lnb = d_in[14];
  const void* Wp = d_in[15];
  const void* bp = d_in[16];

  char* ws = (char*)d_ws;
  float* X      = (float*)(ws + 0L);               // 64 MiB f32 residual
  _Float16* XH  = (_Float16*)(ws + 67108864L);     // fp16 X-high, 32 MiB
  _Float16* XL  = (_Float16*)(ws + 100663296L);    // fp16 X-low*512 / AGh
  _Float16* AGh = (_Float16*)(ws + 100663296L);
  _Float16* ZH  = (_Float16*)(ws + 134217728L);    // Z-high chunk, 4 MiB
  _Float16* ZL  = (_Float16*)(ws + 138412032L);    // Z-low chunk, 4 MiB
  _Float16* Ph  = (_Float16*)(ws + 134217728L);    // Phase B: 8 MiB chunk
  // shared region: Phase A G, Phase B fp16 weights
  float* G32    = (float*)(ws + 142606336L);       // 1 MiB
  _Float16* GH  = (_Float16*)(ws + 143654912L);    // 0.5 MiB
  _Float16* GL  = (_Float16*)(ws + 144179200L);    // 0.5 MiB
  _Float16* Wvh = (_Float16*)(ws + 142606336L);    // Phase B overlays
  _Float16* Woh = (_Float16*)(ws + 143130624L);
  _Float16* W1h = (_Float16*)(ws + 143654912L);    // 2 MiB
  _Float16* W2h = (_Float16*)(ws + 145752064L);    // 2 MiB
  float* MV  = (float*)(ws + 147849216L);
  float* WGT = (float*)(ws + 147980288L);
  int*   DLY = (int*)(ws + 147981312L);
  float* CM  = (float*)(ws + 147982336L);
  float* PB  = (float*)(ws + 148047872L);
  int*  FLAG = (int*)(ws + 148068352L);
  float* S2  = (float*)(ws + 67108864L);           // 64 MiB (FFN XD / final XH)
  _Float16* Hb = (_Float16*)X;                     // FFN hidden (X dead)

  const long AD = (long)LL * DD;   // 524288
  const int M = BB * LL;           // 32768

  detect_k<<<1, 64, 0, stream>>>((const uint32_t*)mark, FLAG);
  conv_embed_k<<<dim3(64, 32), 256, 0, stream>>>(xe, cw, X, FLAG);

  for (int l = 0; l < 3; l++) {
    const long oW = (long)l * DD * DD;
    const long oB = (long)l * DD;
    const long oF = (long)l * DFF * DD;

    // ---- Phase A: delay selection via G-trick + fp16x2 split MFMA ----
    // G'[d,e] = sum_f Wk[f,d] * Wq[f,e]  (biases drop out: tau-invariant)
    gt_k<<<dim3(8, 8), 256, 0, stream>>>(Wk, Wq, oW, G32, FLAG);
    split_k<<<128, 256, 0, stream>>>(G32, GH, GL, 262144);
    split_k<<<8192, 256, 0, stream>>>(X, XH, XL, 16777216);
    hipMemsetAsync(MV, 0, (long)BB * LL * sizeof(float), stream);
    for (int cb = 0; cb < 8; cb++) {
      const long co = (long)cb * 4 * AD;
      gemm_z<<<dim3(4, 32), 256, 0, stream>>>(
          XH + co, XL + co, GH, GL, ZH, ZL, 4096, DD, DD);
      qkmv_hl<<<dim3(8, 8, 4), 256, 0, stream>>>(
          ZH, ZL, XH + co, XL + co, MV + (long)cb * 4 * LL);
    }
    topk_k<<<32, 256, 0, stream>>>(MV, WGT, DLY);

    // ---- Phase B: fp16 MFMA for V / agg / Wo / FFN ----
    wcvt_k<<<128, 256, 0, stream>>>(Wv, oW, Wvh, 262144, FLAG);
    wcvt_k<<<128, 256, 0, stream>>>(Wo, oW, Woh, 262144, FLAG);
    wcvt_k<<<512, 256, 0, stream>>>(Wff1, oF, W1h, 1048576, FLAG);
    wcvt_k<<<512, 256, 0, stream>>>(Wff2, oF, W2h, 1048576, FLAG);

    // V (fp16) per 8-batch chunk -> Ph (over ZH/ZL, dead), agg -> AGh (over XL)
    for (int cb = 0; cb < 4; cb++) {
      const _Float16* xh = XH + (long)cb * 8 * AD;
      gemm_h<1 | 8><<<dim3(4, 64), 256, 0, stream>>>(
          xh, Wvh, bv, oB, nullptr, Ph, 8192, DD, DD, FLAG);
      agg_k<<<dim3(1024, 8), 128, 0, stream>>>(
          Ph, WGT + cb * 48, DLY + cb * 48, AGh + (long)cb * 8 * AD);
    }

    // X = X + AGh @ Wo^T + bo (full M, in-place residual)
    gemm_h<1 | 4><<<dim3(4, 256), 256, 0, stream>>>(
        AGh, Woh, bo, oB, X, X, M, DD, DD, FLAG);

    // x = decomp(X) -> S2 (XH/AGh dead)
    decomp_k<<<dim3(2, 16, 32), 256, 0, stream>>>(X, S2);

    // FFN per 8-batch chunk: XD->fp16 Ph; hidden fp16 -> Hb (X region);
    // S2chunk = S2chunk + (gelu-hidden) @ W2^T
    for (int cb = 0; cb < 4; cb++) {
      float* xd = S2 + (long)cb * 8 * AD;
      acvt_k<<<2048, 256, 0, stream>>>(xd, Ph, 4194304);
      gemm_h<2 | 8><<<dim3(16, 64), 256, 0, stream>>>(
          Ph, W1h, nullptr, 0, nullptr, Hb, 8192, DFF, DD, FLAG);
      gemm_h<4><<<dim3(4, 64), 256, 0, stream>>>(
          Hb, W2h, nullptr, 0, xd, xd, 8192, DD, DFF, FLAG);
    }

    // x = decomp(S2) -> X (next layer input)
    decomp_k<<<dim3(2, 16, 32), 256, 0, stream>>>(S2, X);
  }

  // final special layernorm + gelu + mask + projection
  ln_k<<<dim3(1024, 32), 256, 0, stream>>>(X, lng, lnb, S2, FLAG);
  colmean_k<<<dim3(2, 32), 256, 0, stream>>>(S2, CM);
  geluout_k<<<dim3(1024, 32), 256, 0, stream>>>(S2, CM, mark, X, FLAG);
  proj1_k<<<dim3(16, 10, 32), 256, 0, stream>>>(X, Wp, PB, FLAG);
  proj2_k<<<1, 320, 0, stream>>>(PB, bp, d_out, FLAG);
}

// Round 9
// 4171.703 us; speedup vs baseline: 3.3275x; 1.0206x over previous
//
#include <hip/hip_runtime.h>
#include <cstdint>

// ---------------------------------------------------------------------------
// Autoformer forward — hybrid precision v3:
//   * delay selection via G-trick + fp16x2 split MFMA (R8-verified numerics).
//   * V / Wo / FFN on plain fp16 MFMA.
//   * NEW (R9): all MFMA kernels stage global->LDS via async
//     __builtin_amdgcn_global_load_lds width=16 (m97 ladder: 1.69x).
//     XOR swizzle preserved by permuting the per-lane GLOBAL source address;
//     LDS layout and fragment reads are byte-identical to R8.
// Inputs f32 (runtime-detected from x_mark_enc; bf16 fallback kept).
//
// Workspace (bytes), total ~148.1 MB (R8-proven):
//   X    @ 0          : [32,1024,512] f32 residual; FFN: Hb fp16 hidden
//   XH   @ 67108864   : fp16 X-high (32Mi)
//   XL   @ 100663296  : fp16 X-low*512 (32Mi) / AGh
//   ZH   @ 134217728  : fp16 Z-high chunk 4Mi / Ph 8Mi
//   ZL   @ 138412032  : fp16 Z-low chunk 4Mi
//   SH   @ 142606336  : Phase A: G32+GH+GL | Phase B: Wvh/Woh/W1h/W2h
//   MV   @ 147849216, WGT @ 147980288, DLY @ 147981312, CM @ 147982336,
//   PB   @ 148047872, FLAG @ 148068352
// ---------------------------------------------------------------------------

using u16 = unsigned short;
typedef _Float16 f16x8 __attribute__((ext_vector_type(8)));
typedef float f32x4 __attribute__((ext_vector_type(4)));

#define BB 32
#define LL 1024
#define DD 512
#define DFF 2048

__device__ __forceinline__ float bf2f(u16 u) {
  union { uint32_t i; float f; } v; v.i = ((uint32_t)u) << 16; return v.f;
}
__device__ __forceinline__ u16 f2bf(float f) {
  union { float f; uint32_t i; } v; v.f = f;
  uint32_t r = (v.i + 0x7FFFu + ((v.i >> 16) & 1u)) >> 16;
  return (u16)r;
}
__device__ __forceinline__ float ldi(const void* p, long i, int isf) {
  return isf ? ((const float*)p)[i] : bf2f(((const u16*)p)[i]);
}
__device__ __forceinline__ float gelu_f(float x) {
  return 0.5f * x * (1.0f + erff(x * 0.70710678118654752440f));
}
// async 16B global -> LDS (wave-uniform LDS base + lane*16)
__device__ __forceinline__ void gld16(const void* g, void* l) {
  __builtin_amdgcn_global_load_lds(
      (const __attribute__((address_space(1))) void*)g,
      (__attribute__((address_space(3))) void*)l, 16, 0, 0);
}

union H8 { f16x8 v; uint4 u; _Float16 h[8]; };
union H4 { uint2 u; _Float16 h[4]; };

__global__ void detect_k(const uint32_t* __restrict__ mark, int* __restrict__ FLAG) {
  if (threadIdx.x == 0) FLAG[0] = (mark[0] == 0x3F800000u) ? 1 : 0;
}

// ---------------------------------------------------------------------------
// Conv1d circular embedding. grid (L/16, B), block 256
// ---------------------------------------------------------------------------
__global__ __launch_bounds__(256) void conv_embed_k(
    const void* __restrict__ xe, const void* __restrict__ w,
    float* __restrict__ X, const int* __restrict__ FLAG) {
  const int isf = *FLAG;
  int b = blockIdx.y;
  int l0 = blockIdx.x * 16;
  __shared__ float xs[18][21];
  int tid = threadIdx.x;
  for (int i = tid; i < 18 * 21; i += 256) {
    int r = i / 21, c = i % 21;
    int row = (l0 - 1 + r + LL) & (LL - 1);
    xs[r][c] = ldi(xe, ((long)b * LL + row) * 21 + c, isf);
  }
  __syncthreads();
  for (int d = tid; d < DD; d += 256) {
    float acc[16];
#pragma unroll
    for (int ll = 0; ll < 16; ll++) acc[ll] = 0.0f;
    for (int c = 0; c < 21; c++) {
#pragma unroll
      for (int t = 0; t < 3; t++) {
        float wv = ldi(w, (long)d * 63 + c * 3 + t, isf);
#pragma unroll
        for (int ll = 0; ll < 16; ll++) acc[ll] += wv * xs[t + ll][c];
      }
    }
    for (int ll = 0; ll < 16; ll++)
      X[((long)b * LL + l0 + ll) * DD + d] = acc[ll];
  }
}

// ---------------------------------------------------------------------------
// G'[r,c] = sum_f W1[f,r] * W2[f,c]   (f32 small GEMM, transposed reads)
// grid (8,8), block 256
// ---------------------------------------------------------------------------
__global__ __launch_bounds__(256) void gt_k(
    const void* __restrict__ W1, const void* __restrict__ W2, long off,
    float* __restrict__ G, const int* __restrict__ FLAG) {
  const int isf = *FLAG;
  __shared__ float A1[64][65];
  __shared__ float A2[64][65];
  int c0 = blockIdx.x * 64, r0 = blockIdx.y * 64;
  int tid = threadIdx.x;
  int tx = tid & 15, ty = tid >> 4;
  float acc[4][4] = {};
  for (int f0 = 0; f0 < DD; f0 += 64) {
    for (int i = tid; i < 64 * 64; i += 256) {
      int r = i >> 6, c = i & 63;
      A1[r][c] = ldi(W1, off + (long)(f0 + r) * DD + r0 + c, isf);
      A2[r][c] = ldi(W2, off + (long)(f0 + r) * DD + c0 + c, isf);
    }
    __syncthreads();
    for (int f = 0; f < 64; f++) {
      float av[4], bv[4];
#pragma unroll
      for (int i = 0; i < 4; i++) av[i] = A1[f][ty * 4 + i];
#pragma unroll
      for (int j = 0; j < 4; j++) bv[j] = A2[f][tx * 4 + j];
#pragma unroll
      for (int i = 0; i < 4; i++)
#pragma unroll
        for (int j = 0; j < 4; j++) acc[i][j] = fmaf(av[i], bv[j], acc[i][j]);
    }
    __syncthreads();
  }
#pragma unroll
  for (int i = 0; i < 4; i++)
#pragma unroll
    for (int j = 0; j < 4; j++)
      G[(long)(r0 + ty * 4 + i) * DD + c0 + tx * 4 + j] = acc[i][j];
}

// ---------------------------------------------------------------------------
// split f32 -> (fp16 high, fp16 low*512). 8 elems/thread.
// ---------------------------------------------------------------------------
__global__ __launch_bounds__(256) void split_k(const float* __restrict__ src,
                                               _Float16* __restrict__ dh,
                                               _Float16* __restrict__ dl, int n) {
  long i = ((long)blockIdx.x * 256 + threadIdx.x) * 8;
  if (i >= n) return;
  float4 a = *(const float4*)(src + i);
  float4 b = *(const float4*)(src + i + 4);
  float x[8] = {a.x, a.y, a.z, a.w, b.x, b.y, b.z, b.w};
  H8 h, l;
#pragma unroll
  for (int j = 0; j < 8; j++) {
    _Float16 hv = (_Float16)x[j];
    h.h[j] = hv;
    l.h[j] = (_Float16)((x[j] - (float)hv) * 512.0f);
  }
  *(uint4*)(dh + i) = h.u;
  *(uint4*)(dl + i) = l.u;
}

// convert f32 -> fp16 (plain), 8 elems/thread
__global__ __launch_bounds__(256) void acvt_k(const float* __restrict__ src,
                                              _Float16* __restrict__ dst, int n) {
  long i = ((long)blockIdx.x * 256 + threadIdx.x) * 8;
  if (i >= n) return;
  float4 a = *(const float4*)(src + i);
  float4 b = *(const float4*)(src + i + 4);
  H8 r;
  r.h[0] = (_Float16)a.x; r.h[1] = (_Float16)a.y;
  r.h[2] = (_Float16)a.z; r.h[3] = (_Float16)a.w;
  r.h[4] = (_Float16)b.x; r.h[5] = (_Float16)b.y;
  r.h[6] = (_Float16)b.z; r.h[7] = (_Float16)b.w;
  *(uint4*)(dst + i) = r.u;
}

// convert external weight (f32 or bf16 per FLAG) -> fp16
__global__ __launch_bounds__(256) void wcvt_k(const void* __restrict__ src, long off,
                                              _Float16* __restrict__ dst, int n,
                                              const int* __restrict__ FLAG) {
  const int isf = *FLAG;
  long i = ((long)blockIdx.x * 256 + threadIdx.x) * 8;
  if (i >= n) return;
  H8 r;
  if (isf) {
    const float* s = (const float*)src + off + i;
    float4 a = *(const float4*)s;
    float4 b = *(const float4*)(s + 4);
    r.h[0] = (_Float16)a.x; r.h[1] = (_Float16)a.y;
    r.h[2] = (_Float16)a.z; r.h[3] = (_Float16)a.w;
    r.h[4] = (_Float16)b.x; r.h[5] = (_Float16)b.y;
    r.h[6] = (_Float16)b.z; r.h[7] = (_Float16)b.w;
  } else {
    const u16* s = (const u16*)src + off + i;
    uint4 u = *(const uint4*)s;
    r.h[0] = (_Float16)bf2f((u16)(u.x & 0xffff));
    r.h[1] = (_Float16)bf2f((u16)(u.x >> 16));
    r.h[2] = (_Float16)bf2f((u16)(u.y & 0xffff));
    r.h[3] = (_Float16)bf2f((u16)(u.y >> 16));
    r.h[4] = (_Float16)bf2f((u16)(u.z & 0xffff));
    r.h[5] = (_Float16)bf2f((u16)(u.z >> 16));
    r.h[6] = (_Float16)bf2f((u16)(u.w & 0xffff));
    r.h[7] = (_Float16)bf2f((u16)(u.w >> 16));
  }
  *(uint4*)(dst + i) = r.u;
}

// ---------------------------------------------------------------------------
// Async-staging lane mapping (all MFMA kernels):
//   16B block ib of a [128 rows x 32 cols fp16] tile lives at LDS offset ib*16.
//   Wave wvi call j covers blocks [(2*wvi+j)*64, +64); lane handles
//   ib = (2*wvi+j)*64 + lane. Row = ib>>2; LDS colseg = ib&3; the GLOBAL
//   source colseg is (ib&3) ^ ((row>>1)&3)  — implements R8's XOR swizzle.
// ---------------------------------------------------------------------------

// ---------------------------------------------------------------------------
// split-fp16 MFMA GEMM: Z = A @ W^T, A=(Ah+Al/512), W=(Bh+Bl/512).
// Writes split (Zh, Zl*512) fp16.  tile 128x128, BK=32, 256 thr.
// ---------------------------------------------------------------------------
__global__ __launch_bounds__(256) void gemm_z(
    const _Float16* __restrict__ Ah, const _Float16* __restrict__ Al,
    const _Float16* __restrict__ Bh, const _Float16* __restrict__ Bl,
    _Float16* __restrict__ Zh, _Float16* __restrict__ Zl,
    int M, int N, int K) {
  __shared__ __align__(16) _Float16 AsH[128 * 32];
  __shared__ __align__(16) _Float16 AsL[128 * 32];
  __shared__ __align__(16) _Float16 BsH[128 * 32];
  __shared__ __align__(16) _Float16 BsL[128 * 32];
  const int n0 = blockIdx.x * 128, m0 = blockIdx.y * 128;
  const int tid = threadIdx.x;
  const int lane = tid & 63, wvi = tid >> 6;
  const int wm = (wvi >> 1) * 64, wn = (wvi & 1) * 64;
  const int l15 = lane & 15, quad = lane >> 4;
  // async staging mapping
  const int ib = wvi * 128 + lane;
  const int r0 = ib >> 2, r1 = r0 + 16;
  const int c0 = ((ib & 3) ^ ((r0 >> 1) & 3)) * 8;
  const int c1 = ((ib & 3) ^ ((r1 >> 1) & 3)) * 8;
  const int lb0 = wvi * 1024, lb1 = wvi * 1024 + 512;
  const long ga0 = (long)(m0 + r0) * K + c0;
  const long ga1 = (long)(m0 + r1) * K + c1;
  const long gb0 = (long)(n0 + r0) * K + c0;
  const long gb1 = (long)(n0 + r1) * K + c1;
  f32x4 aM[4][4], aC[4][4];
#pragma unroll
  for (int i = 0; i < 4; i++)
#pragma unroll
    for (int j = 0; j < 4; j++) {
      aM[i][j] = (f32x4){0.f, 0.f, 0.f, 0.f};
      aC[i][j] = (f32x4){0.f, 0.f, 0.f, 0.f};
    }
  for (int k0 = 0; k0 < K; k0 += 32) {
    __syncthreads();
    gld16(Ah + ga0 + k0, AsH + lb0);
    gld16(Ah + ga1 + k0, AsH + lb1);
    gld16(Al + ga0 + k0, AsL + lb0);
    gld16(Al + ga1 + k0, AsL + lb1);
    gld16(Bh + gb0 + k0, BsH + lb0);
    gld16(Bh + gb1 + k0, BsH + lb1);
    gld16(Bl + gb0 + k0, BsL + lb0);
    gld16(Bl + gb1 + k0, BsL + lb1);
    __syncthreads();
    f16x8 fah[4], fal[4], fbh[4], fbl[4];
#pragma unroll
    for (int mi = 0; mi < 4; mi++) {
      int r = wm + mi * 16 + l15;
      int o = r * 32 + ((quad ^ ((r >> 1) & 3)) * 8);
      fah[mi] = *(const f16x8*)&AsH[o];
      fal[mi] = *(const f16x8*)&AsL[o];
    }
#pragma unroll
    for (int ni = 0; ni < 4; ni++) {
      int r = wn + ni * 16 + l15;
      int o = r * 32 + ((quad ^ ((r >> 1) & 3)) * 8);
      fbh[ni] = *(const f16x8*)&BsH[o];
      fbl[ni] = *(const f16x8*)&BsL[o];
    }
#pragma unroll
    for (int mi = 0; mi < 4; mi++)
#pragma unroll
      for (int ni = 0; ni < 4; ni++) {
        aM[mi][ni] = __builtin_amdgcn_mfma_f32_16x16x32_f16(
            fah[mi], fbh[ni], aM[mi][ni], 0, 0, 0);
        aC[mi][ni] = __builtin_amdgcn_mfma_f32_16x16x32_f16(
            fah[mi], fbl[ni], aC[mi][ni], 0, 0, 0);
        aC[mi][ni] = __builtin_amdgcn_mfma_f32_16x16x32_f16(
            fal[mi], fbh[ni], aC[mi][ni], 0, 0, 0);
      }
  }
#pragma unroll
  for (int mi = 0; mi < 4; mi++) {
    int rowg = m0 + wm + mi * 16 + quad * 4;
#pragma unroll
    for (int ni = 0; ni < 4; ni++) {
      int colg = n0 + wn + ni * 16 + l15;
#pragma unroll
      for (int rr = 0; rr < 4; rr++) {
        long off = (long)(rowg + rr) * N + colg;
        float z = aM[mi][ni][rr] + aC[mi][ni][rr] * (1.0f / 512.0f);
        _Float16 zh = (_Float16)z;
        Zh[off] = zh;
        Zl[off] = (_Float16)((z - (float)zh) * 512.0f);
      }
    }
  }
}

// ---------------------------------------------------------------------------
// split-fp16 MFMA Z.X^T with fused wrapped-diagonal mean reduction:
//   MV[b,tau] += (1/512) * sum_t Z[b,(t+tau)%L,:] . X[b,t,:]
// grid (8, 8, NB), block 256.  MV (chunk-offset) zeroed beforehand.
// ---------------------------------------------------------------------------
__global__ __launch_bounds__(256) void qkmv_hl(
    const _Float16* __restrict__ Zh, const _Float16* __restrict__ Zl,
    const _Float16* __restrict__ Xh, const _Float16* __restrict__ Xl,
    float* __restrict__ MV) {
  __shared__ __align__(16) _Float16 AsH[128 * 32];
  __shared__ __align__(16) _Float16 AsL[128 * 32];
  __shared__ __align__(16) _Float16 BsH[128 * 32];
  __shared__ __align__(16) _Float16 BsL[128 * 32];
  __shared__ float diag[255];
  const int bz = blockIdx.z;
  const long bb = (long)bz * LL * DD;
  const int n0 = blockIdx.x * 128, m0 = blockIdx.y * 128;
  const int tid = threadIdx.x;
  const int lane = tid & 63, wvi = tid >> 6;
  const int wm = (wvi >> 1) * 64, wn = (wvi & 1) * 64;
  const int l15 = lane & 15, quad = lane >> 4;
  const int ib = wvi * 128 + lane;
  const int r0 = ib >> 2, r1 = r0 + 16;
  const int c0 = ((ib & 3) ^ ((r0 >> 1) & 3)) * 8;
  const int c1 = ((ib & 3) ^ ((r1 >> 1) & 3)) * 8;
  const int lb0 = wvi * 1024, lb1 = wvi * 1024 + 512;
  const long ga0 = bb + (long)(m0 + r0) * DD + c0;
  const long ga1 = bb + (long)(m0 + r1) * DD + c1;
  const long gb0 = bb + (long)(n0 + r0) * DD + c0;
  const long gb1 = bb + (long)(n0 + r1) * DD + c1;
  if (tid < 255) diag[tid] = 0.0f;
  f32x4 aM[4][4], aC[4][4];
#pragma unroll
  for (int i = 0; i < 4; i++)
#pragma unroll
    for (int j = 0; j < 4; j++) {
      aM[i][j] = (f32x4){0.f, 0.f, 0.f, 0.f};
      aC[i][j] = (f32x4){0.f, 0.f, 0.f, 0.f};
    }
  for (int k0 = 0; k0 < DD; k0 += 32) {
    __syncthreads();
    gld16(Zh + ga0 + k0, AsH + lb0);
    gld16(Zh + ga1 + k0, AsH + lb1);
    gld16(Zl + ga0 + k0, AsL + lb0);
    gld16(Zl + ga1 + k0, AsL + lb1);
    gld16(Xh + gb0 + k0, BsH + lb0);
    gld16(Xh + gb1 + k0, BsH + lb1);
    gld16(Xl + gb0 + k0, BsL + lb0);
    gld16(Xl + gb1 + k0, BsL + lb1);
    __syncthreads();
    f16x8 fah[4], fal[4], fbh[4], fbl[4];
#pragma unroll
    for (int mi = 0; mi < 4; mi++) {
      int r = wm + mi * 16 + l15;
      int o = r * 32 + ((quad ^ ((r >> 1) & 3)) * 8);
      fah[mi] = *(const f16x8*)&AsH[o];
      fal[mi] = *(const f16x8*)&AsL[o];
    }
#pragma unroll
    for (int ni = 0; ni < 4; ni++) {
      int r = wn + ni * 16 + l15;
      int o = r * 32 + ((quad ^ ((r >> 1) & 3)) * 8);
      fbh[ni] = *(const f16x8*)&BsH[o];
      fbl[ni] = *(const f16x8*)&BsL[o];
    }
#pragma unroll
    for (int mi = 0; mi < 4; mi++)
#pragma unroll
      for (int ni = 0; ni < 4; ni++) {
        aM[mi][ni] = __builtin_amdgcn_mfma_f32_16x16x32_f16(
            fah[mi], fbh[ni], aM[mi][ni], 0, 0, 0);
        aC[mi][ni] = __builtin_amdgcn_mfma_f32_16x16x32_f16(
            fah[mi], fbl[ni], aC[mi][ni], 0, 0, 0);
        aC[mi][ni] = __builtin_amdgcn_mfma_f32_16x16x32_f16(
            fal[mi], fbh[ni], aC[mi][ni], 0, 0, 0);
      }
  }
  // element (m,n): m = wm+mi*16+quad*4+rr, n = wn+ni*16+l15; dl = m-n
#pragma unroll
  for (int g = -3; g <= 3; g++) {
#pragma unroll
    for (int rr = 0; rr < 4; rr++) {
      float s = 0.0f;
#pragma unroll
      for (int mi = 0; mi < 4; mi++) {
        int ni = mi - g;
        if (ni >= 0 && ni < 4)
          s += aM[mi][ni][rr] + aC[mi][ni][rr] * (1.0f / 512.0f);
      }
      int d = 127 + (wm - wn) + g * 16 + quad * 4 + rr - l15;
      atomicAdd(&diag[d], s);
    }
  }
  __syncthreads();
  if (tid < 255) {
    int tau = (m0 - n0 + tid - 127 + LL) & (LL - 1);
    atomicAdd(&MV[(long)bz * LL + tau], diag[tid] * (1.0f / 512.0f));
  }
}

// ---------------------------------------------------------------------------
// fp16 MFMA GEMM: C[M,N] = act( A[M,K] @ W[N,K]^T + bias + R )
// FLAGS: 1=bias 2=gelu 4=residual 8=out-fp16
// ---------------------------------------------------------------------------
template <int FLAGS>
__global__ __launch_bounds__(256) void gemm_h(
    const _Float16* __restrict__ A, const _Float16* __restrict__ W,
    const void* __restrict__ biasBase, long bOff,
    const float* __restrict__ R, void* __restrict__ Cout,
    int M, int N, int K, const int* __restrict__ FLAG) {
  constexpr bool HAS_BIAS = (FLAGS & 1) != 0;
  constexpr bool DO_GELU = (FLAGS & 2) != 0;
  constexpr bool DO_RES = (FLAGS & 4) != 0;
  constexpr bool OUT_H = (FLAGS & 8) != 0;
  __shared__ __align__(16) _Float16 As[128 * 32];
  __shared__ __align__(16) _Float16 Bs[128 * 32];
  const int n0 = blockIdx.x * 128, m0 = blockIdx.y * 128;
  const int tid = threadIdx.x;
  const int lane = tid & 63, wvi = tid >> 6;
  const int wm = (wvi >> 1) * 64, wn = (wvi & 1) * 64;
  const int l15 = lane & 15, quad = lane >> 4;
  const int ib = wvi * 128 + lane;
  const int r0 = ib >> 2, r1 = r0 + 16;
  const int c0 = ((ib & 3) ^ ((r0 >> 1) & 3)) * 8;
  const int c1 = ((ib & 3) ^ ((r1 >> 1) & 3)) * 8;
  const int lb0 = wvi * 1024, lb1 = wvi * 1024 + 512;
  const _Float16* ga0 = A + (long)(m0 + r0) * K + c0;
  const _Float16* ga1 = A + (long)(m0 + r1) * K + c1;
  const _Float16* gb0 = W + (long)(n0 + r0) * K + c0;
  const _Float16* gb1 = W + (long)(n0 + r1) * K + c1;
  f32x4 acc[4][4];
#pragma unroll
  for (int i = 0; i < 4; i++)
#pragma unroll
    for (int j = 0; j < 4; j++) acc[i][j] = (f32x4){0.f, 0.f, 0.f, 0.f};
  for (int k0 = 0; k0 < K; k0 += 32) {
    __syncthreads();
    gld16(ga0 + k0, As + lb0);
    gld16(ga1 + k0, As + lb1);
    gld16(gb0 + k0, Bs + lb0);
    gld16(gb1 + k0, Bs + lb1);
    __syncthreads();
    f16x8 af[4], bfr[4];
#pragma unroll
    for (int mi = 0; mi < 4; mi++) {
      int r = wm + mi * 16 + l15;
      af[mi] = *(const f16x8*)&As[r * 32 + ((quad ^ ((r >> 1) & 3)) * 8)];
    }
#pragma unroll
    for (int ni = 0; ni < 4; ni++) {
      int r = wn + ni * 16 + l15;
      bfr[ni] = *(const f16x8*)&Bs[r * 32 + ((quad ^ ((r >> 1) & 3)) * 8)];
    }
#pragma unroll
    for (int mi = 0; mi < 4; mi++)
#pragma unroll
      for (int ni = 0; ni < 4; ni++)
        acc[mi][ni] = __builtin_amdgcn_mfma_f32_16x16x32_f16(
            af[mi], bfr[ni], acc[mi][ni], 0, 0, 0);
  }
  float bcol[4];
  if constexpr (HAS_BIAS) {
    const int isf = *FLAG;
#pragma unroll
    for (int ni = 0; ni < 4; ni++)
      bcol[ni] = ldi(biasBase, bOff + n0 + wn + ni * 16 + l15, isf);
  }
#pragma unroll
  for (int mi = 0; mi < 4; mi++) {
    int rowg = m0 + wm + mi * 16 + quad * 4;
#pragma unroll
    for (int ni = 0; ni < 4; ni++) {
      int colg = n0 + wn + ni * 16 + l15;
#pragma unroll
      for (int rr = 0; rr < 4; rr++) {
        long off = (long)(rowg + rr) * N + colg;
        float v = acc[mi][ni][rr];
        if constexpr (HAS_BIAS) v += bcol[ni];
        if constexpr (DO_RES) v += R[off];
        if constexpr (DO_GELU) v = gelu_f(v);
        if constexpr (OUT_H) ((_Float16*)Cout)[off] = (_Float16)v;
        else ((float*)Cout)[off] = v;
      }
    }
  }
}

// ---------------------------------------------------------------------------
// top-6 of MV[b,:] + softmax.  grid (32), block 256
// ---------------------------------------------------------------------------
__global__ __launch_bounds__(256) void topk_k(const float* __restrict__ MV,
                                              float* __restrict__ WGT,
                                              int* __restrict__ DLY) {
  int b = blockIdx.x;
  __shared__ float vals[LL];
  __shared__ float rv[256];
  __shared__ int ri[256];
  __shared__ float selv[6];
  int tid = threadIdx.x;
  for (int i = tid; i < LL; i += 256) vals[i] = MV[(long)b * LL + i];
  __syncthreads();
  for (int it = 0; it < 6; it++) {
    float bv = -1e30f;
    int bi = LL - 1;
    for (int i = tid; i < LL; i += 256) {
      float v = vals[i];
      if (v > bv || (v == bv && i < bi)) { bv = v; bi = i; }
    }
    rv[tid] = bv; ri[tid] = bi;
    __syncthreads();
    for (int st = 128; st > 0; st >>= 1) {
      if (tid < st) {
        float ov = rv[tid + st]; int oi = ri[tid + st];
        if (ov > rv[tid] || (ov == rv[tid] && oi < ri[tid])) {
          rv[tid] = ov; ri[tid] = oi;
        }
      }
      __syncthreads();
    }
    if (tid == 0) {
      selv[it] = rv[0];
      DLY[b * 6 + it] = ri[0];
      vals[ri[0]] = -1e30f;
    }
    __syncthreads();
  }
  if (tid == 0) {
    float mx = selv[0];
    float e[6], s = 0.0f;
    for (int i = 0; i < 6; i++) { e[i] = expf(selv[i] - mx); s += e[i]; }
    for (int i = 0; i < 6; i++) WGT[b * 6 + i] = e[i] / s;
  }
}

// ---------------------------------------------------------------------------
// time-delay aggregation, fp16 in/out (chunk-local): grid (1024, NB), block 128
// ---------------------------------------------------------------------------
__global__ __launch_bounds__(128) void agg_k(const _Float16* __restrict__ V,
                                             const float* __restrict__ WGT,
                                             const int* __restrict__ DLY,
                                             _Float16* __restrict__ O) {
  int l = blockIdx.x, b = blockIdx.y;
  int tid = threadIdx.x;
  float w[6]; int dl[6];
#pragma unroll
  for (int i = 0; i < 6; i++) { w[i] = WGT[b * 6 + i]; dl[i] = DLY[b * 6 + i]; }
  long base = (long)b * LL * DD;
  int d = tid * 4;
  float a0 = 0, a1 = 0, a2 = 0, a3 = 0;
#pragma unroll
  for (int i = 0; i < 6; i++) {
    int row = (l + dl[i]) & (LL - 1);
    H4 t; t.u = *(const uint2*)&V[base + (long)row * DD + d];
    a0 += w[i] * (float)t.h[0];
    a1 += w[i] * (float)t.h[1];
    a2 += w[i] * (float)t.h[2];
    a3 += w[i] * (float)t.h[3];
  }
  H4 r;
  r.h[0] = (_Float16)a0; r.h[1] = (_Float16)a1;
  r.h[2] = (_Float16)a2; r.h[3] = (_Float16)a3;
  *(uint2*)&O[base + (long)l * DD + d] = r.u;
}

// ---------------------------------------------------------------------------
// series_decomp residual. grid (2, 16, 32), block 256
// ---------------------------------------------------------------------------
__global__ __launch_bounds__(256) void decomp_k(const float* __restrict__ Xin,
                                                float* __restrict__ Out) {
  int d = blockIdx.x * 256 + threadIdx.x;
  int l0 = blockIdx.y * 64;
  int b = blockIdx.z;
  const float* xb = Xin + (long)b * LL * DD + d;
  float* ob = Out + (long)b * LL * DD + d;
  float wsum = 0.0f;
  for (int j = l0 - 12; j <= l0 + 12; j++) {
    int jj = min(max(j, 0), LL - 1);
    wsum += xb[(long)jj * DD];
  }
  for (int l = l0; l < l0 + 64; l++) {
    float xv = xb[(long)l * DD];
    ob[(long)l * DD] = xv - wsum * (1.0f / 25.0f);
    int ja = min(l + 13, LL - 1);
    int jr = max(l - 12, 0);
    wsum += xb[(long)ja * DD] - xb[(long)jr * DD];
  }
}

// special layernorm. grid (1024,32), block 256
__global__ __launch_bounds__(256) void ln_k(const float* __restrict__ X,
                                            const void* __restrict__ g,
                                            const void* __restrict__ be,
                                            float* __restrict__ XH,
                                            const int* __restrict__ FLAG) {
  const int isf = *FLAG;
  int l = blockIdx.x, b = blockIdx.y;
  const float* xr = X + ((long)b * LL + l) * DD;
  int tid = threadIdx.x;
  float x0 = xr[tid], x1 = xr[tid + 256];
  __shared__ float rs[256], rq[256];
  rs[tid] = x0 + x1;
  rq[tid] = x0 * x0 + x1 * x1;
  __syncthreads();
  for (int st = 128; st > 0; st >>= 1) {
    if (tid < st) { rs[tid] += rs[tid + st]; rq[tid] += rq[tid + st]; }
    __syncthreads();
  }
  float mu = rs[0] * (1.0f / 512.0f);
  float var = rq[0] * (1.0f / 512.0f) - mu * mu;
  float rstd = rsqrtf(var + 1e-5f);
  float* o = XH + ((long)b * LL + l) * DD;
  o[tid] = (x0 - mu) * rstd * ldi(g, tid, isf) + ldi(be, tid, isf);
  o[tid + 256] = (x1 - mu) * rstd * ldi(g, tid + 256, isf) + ldi(be, tid + 256, isf);
}

// colmean. grid (2,32), block 256
__global__ __launch_bounds__(256) void colmean_k(const float* __restrict__ XH,
                                                 float* __restrict__ CM) {
  int d = blockIdx.x * 256 + threadIdx.x;
  int b = blockIdx.y;
  const float* p = XH + (long)b * LL * DD + d;
  float s = 0.0f;
  for (int l = 0; l < LL; l++) s += p[(long)l * DD];
  CM[(long)b * DD + d] = s * (1.0f / 1024.0f);
}

// OUT = gelu(XH - CM) * mark. grid (1024,32), block 256
__global__ __launch_bounds__(256) void geluout_k(const float* __restrict__ XH,
                                                 const float* __restrict__ CM,
                                                 const void* __restrict__ mark,
                                                 float* __restrict__ OUT,
                                                 const int* __restrict__ FLAG) {
  const int isf = *FLAG;
  int l = blockIdx.x, b = blockIdx.y;
  int tid = threadIdx.x;
  float mk = ldi(mark, (long)b * LL + l, isf);
  long off = ((long)b * LL + l) * DD;
#pragma unroll
  for (int h = 0; h < 2; h++) {
    int d = tid + h * 256;
    float v = XH[off + d] - CM[(long)b * DD + d];
    OUT[off + d] = gelu_f(v) * mk;
  }
}

// proj stage 1. grid (16, 10, 32), block 256
__global__ __launch_bounds__(256) void proj1_k(const float* __restrict__ OUT,
                                               const void* __restrict__ Wp,
                                               float* __restrict__ PB,
                                               const int* __restrict__ FLAG) {
  const int isf = *FLAG;
  int chunk = blockIdx.x, n = blockIdx.y, b = blockIdx.z;
  long e0 = (long)chunk * 32768;
  const float* xb = OUT + (long)b * 524288 + e0;
  long wbase = (long)n * 524288 + e0;
  int tid = threadIdx.x;
  float s = 0.0f;
  if (isf) {
    const float* wr = (const float*)Wp + wbase;
    for (int i = tid * 4; i < 32768; i += 1024) {
      float4 x = *(const float4*)&xb[i];
      float4 w = *(const float4*)&wr[i];
      s += x.x * w.x + x.y * w.y + x.z * w.z + x.w * w.w;
    }
  } else {
    const u16* wr = (const u16*)Wp + wbase;
    for (int i = tid * 4; i < 32768; i += 1024) {
      float4 x = *(const float4*)&xb[i];
      uint2 u = *(const uint2*)&wr[i];
      s += x.x * bf2f((u16)(u.x & 0xffff)) + x.y * bf2f((u16)(u.x >> 16)) +
           x.z * bf2f((u16)(u.y & 0xffff)) + x.w * bf2f((u16)(u.y >> 16));
    }
  }
  __shared__ float red[256];
  red[tid] = s;
  __syncthreads();
  for (int st = 128; st > 0; st >>= 1) {
    if (tid < st) red[tid] += red[tid + st];
    __syncthreads();
  }
  if (tid == 0) PB[((long)b * 10 + n) * 16 + chunk] = red[0];
}

// proj stage 2: logits -> out (dtype per FLAG). grid (1), block 320
__global__ __launch_bounds__(320) void proj2_k(const float* __restrict__ PB,
                                               const void* __restrict__ bp,
                                               void* __restrict__ out,
                                               const int* __restrict__ FLAG) {
  const int isf = *FLAG;
  int id = threadIdx.x;
  int b = id / 10, n = id % 10;
  float s = ldi(bp, n, isf);
  for (int c = 0; c < 16; c++) s += PB[((long)b * 10 + n) * 16 + c];
  if (isf) ((float*)out)[b * 10 + n] = s;
  else ((u16*)out)[b * 10 + n] = f2bf(s);
}

// ---------------------------------------------------------------------------
extern "C" void kernel_launch(void* const* d_in, const int* in_sizes, int n_in,
                              void* d_out, int out_size, void* d_ws, size_t ws_size,
                              hipStream_t stream) {
  const void* xe = d_in[0];
  const void* mark = d_in[1];
  const void* cw = d_in[2];
  const void* Wq = d_in[3];
  const void* Wk = d_in[5];
  const void* Wv = d_in[7];
  const void* bv = d_in[8];
  const void* Wo = d_in[9];
  const void* bo = d_in[10];
  const void* Wff1 = d_in[11];
  const void* Wff2 = d_in[12];
  const void* lng = d_in[13];
  const void* lnb = d_in[14];
  const void* Wp = d_in[15];
  const void* bp = d_in[16];

  char* ws = (char*)d_ws;
  float* X      = (float*)(ws + 0L);               // 64 MiB f32 residual
  _Float16* XH  = (_Float16*)(ws + 67108864L);     // fp16 X-high, 32 MiB
  _Float16* XL  = (_Float16*)(ws + 100663296L);    // fp16 X-low*512 / AGh
  _Float16* AGh = (_Float16*)(ws + 100663296L);
  _Float16* ZH  = (_Float16*)(ws + 134217728L);    // Z-high chunk, 4 MiB
  _Float16* ZL  = (_Float16*)(ws + 138412032L);    // Z-low chunk, 4 MiB
  _Float16* Ph  = (_Float16*)(ws + 134217728L);    // Phase B: 8 MiB chunk
  float* G32    = (float*)(ws + 142606336L);       // 1 MiB
  _Float16* GH  = (_Float16*)(ws + 143654912L);    // 0.5 MiB
  _Float16* GL  = (_Float16*)(ws + 144179200L);    // 0.5 MiB
  _Float16* Wvh = (_Float16*)(ws + 142606336L);    // Phase B overlays
  _Float16* Woh = (_Float16*)(ws + 143130624L);
  _Float16* W1h = (_Float16*)(ws + 143654912L);    // 2 MiB
  _Float16* W2h = (_Float16*)(ws + 145752064L);    // 2 MiB
  float* MV  = (float*)(ws + 147849216L);
  float* WGT = (float*)(ws + 147980288L);
  int*   DLY = (int*)(ws + 147981312L);
  float* CM  = (float*)(ws + 147982336L);
  float* PB  = (float*)(ws + 148047872L);
  int*  FLAG = (int*)(ws + 148068352L);
  float* S2  = (float*)(ws + 67108864L);           // 64 MiB (FFN XD / final XH)
  _Float16* Hb = (_Float16*)X;                     // FFN hidden (X dead)

  const long AD = (long)LL * DD;   // 524288
  const int M = BB * LL;           // 32768

  detect_k<<<1, 64, 0, stream>>>((const uint32_t*)mark, FLAG);
  conv_embed_k<<<dim3(64, 32), 256, 0, stream>>>(xe, cw, X, FLAG);

  for (int l = 0; l < 3; l++) {
    const long oW = (long)l * DD * DD;
    const long oB = (long)l * DD;
    const long oF = (long)l * DFF * DD;

    // ---- Phase A: delay selection via G-trick + fp16x2 split MFMA ----
    gt_k<<<dim3(8, 8), 256, 0, stream>>>(Wk, Wq, oW, G32, FLAG);
    split_k<<<128, 256, 0, stream>>>(G32, GH, GL, 262144);
    split_k<<<8192, 256, 0, stream>>>(X, XH, XL, 16777216);
    hipMemsetAsync(MV, 0, (long)BB * LL * sizeof(float), stream);
    for (int cb = 0; cb < 8; cb++) {
      const long co = (long)cb * 4 * AD;
      gemm_z<<<dim3(4, 32), 256, 0, stream>>>(
          XH + co, XL + co, GH, GL, ZH, ZL, 4096, DD, DD);
      qkmv_hl<<<dim3(8, 8, 4), 256, 0, stream>>>(
          ZH, ZL, XH + co, XL + co, MV + (long)cb * 4 * LL);
    }
    topk_k<<<32, 256, 0, stream>>>(MV, WGT, DLY);

    // ---- Phase B: fp16 MFMA for V / agg / Wo / FFN ----
    wcvt_k<<<128, 256, 0, stream>>>(Wv, oW, Wvh, 262144, FLAG);
    wcvt_k<<<128, 256, 0, stream>>>(Wo, oW, Woh, 262144, FLAG);
    wcvt_k<<<512, 256, 0, stream>>>(Wff1, oF, W1h, 1048576, FLAG);
    wcvt_k<<<512, 256, 0, stream>>>(Wff2, oF, W2h, 1048576, FLAG);

    // V (fp16) per 8-batch chunk -> Ph (over ZH/ZL, dead), agg -> AGh (over XL)
    for (int cb = 0; cb < 4; cb++) {
      const _Float16* xh = XH + (long)cb * 8 * AD;
      gemm_h<1 | 8><<<dim3(4, 64), 256, 0, stream>>>(
          xh, Wvh, bv, oB, nullptr, Ph, 8192, DD, DD, FLAG);
      agg_k<<<dim3(1024, 8), 128, 0, stream>>>(
          Ph, WGT + cb * 48, DLY + cb * 48, AGh + (long)cb * 8 * AD);
    }

    // X = X + AGh @ Wo^T + bo (full M, in-place residual)
    gemm_h<1 | 4><<<dim3(4, 256), 256, 0, stream>>>(
        AGh, Woh, bo, oB, X, X, M, DD, DD, FLAG);

    // x = decomp(X) -> S2 (XH/AGh dead)
    decomp_k<<<dim3(2, 16, 32), 256, 0, stream>>>(X, S2);

    // FFN per 8-batch chunk: XD->fp16 Ph; hidden fp16 -> Hb (X region);
    // S2chunk = S2chunk + (gelu-hidden) @ W2^T
    for (int cb = 0; cb < 4; cb++) {
      float* xd = S2 + (long)cb * 8 * AD;
      acvt_k<<<2048, 256, 0, stream>>>(xd, Ph, 4194304);
      gemm_h<2 | 8><<<dim3(16, 64), 256, 0, stream>>>(
          Ph, W1h, nullptr, 0, nullptr, Hb, 8192, DFF, DD, FLAG);
      gemm_h<4><<<dim3(4, 64), 256, 0, stream>>>(
          Hb, W2h, nullptr, 0, xd, xd, 8192, DD, DFF, FLAG);
    }

    // x = decomp(S2) -> X (next layer input)
    decomp_k<<<dim3(2, 16, 32), 256, 0, stream>>>(S2, X);
  }

  // final special layernorm + gelu + mask + projection
  ln_k<<<dim3(1024, 32), 256, 0, stream>>>(X, lng, lnb, S2, FLAG);
  colmean_k<<<dim3(2, 32), 256, 0, stream>>>(S2, CM);
  geluout_k<<<dim3(1024, 32), 256, 0, stream>>>(S2, CM, mark, X, FLAG);
  proj1_k<<<dim3(16, 10, 32), 256, 0, stream>>>(X, Wp, PB, FLAG);
  proj2_k<<<1, 320, 0, stream>>>(PB, bp, d_out, FLAG);
}

// Round 11
// 4048.277 us; speedup vs baseline: 3.4289x; 1.0305x over previous
//
#include <hip/hip_runtime.h>
#include <cstdint>

// ---------------------------------------------------------------------------
// Autoformer forward — hybrid precision v5 (R10 races fixed):
//   * delay selection via G-trick + fp16x2 split MFMA (R8/R9-verified).
//   * V / Wo / FFN on fp16 MFMA, BK=64.
//   * conv_embed reads pre-transposed weights (coalesced) + fused X split.
//   * decomp/split/convert passes use R9's proven (race-free) dataflow.
// Inputs f32 (runtime-detected from x_mark_enc; bf16 fallback kept).
//
// Workspace (bytes), total ~148.1 MB (R8/R9-proven):
//   X    @ 0          : f32 residual 64Mi; FFN phase: Hb fp16 hidden (0..32Mi)
//   XH   @ 67108864   : fp16 X-high 32Mi   | FFN phase: S2 f32 full 64Mi
//   XL   @ 100663296  : fp16 X-low*512 32Mi / AGh
//   ZH   @ 134217728  : fp16 Z-high chunk 4Mi \ Ph 8Mi (V chunk / FFN in chunk)
//   ZL   @ 138412032  : fp16 Z-low chunk 4Mi  /
//   SH   @ 142606336  : Phase A: wT/G32(1Mi)+GH(.5)+GL(.5) | B: Wvh/Woh/W1h/W2h
//   MV   @ 147849216, WGT @ 147980288, DLY @ 147981312, CM @ 147982336,
//   PB   @ 148047872, FLAG @ 148068352
// ---------------------------------------------------------------------------

using u16 = unsigned short;
typedef _Float16 f16x8 __attribute__((ext_vector_type(8)));
typedef float f32x4 __attribute__((ext_vector_type(4)));

#define BB 32
#define LL 1024
#define DD 512
#define DFF 2048

__device__ __forceinline__ float bf2f(u16 u) {
  union { uint32_t i; float f; } v; v.i = ((uint32_t)u) << 16; return v.f;
}
__device__ __forceinline__ u16 f2bf(float f) {
  union { float f; uint32_t i; } v; v.f = f;
  uint32_t r = (v.i + 0x7FFFu + ((v.i >> 16) & 1u)) >> 16;
  return (u16)r;
}
__device__ __forceinline__ float ldi(const void* p, long i, int isf) {
  return isf ? ((const float*)p)[i] : bf2f(((const u16*)p)[i]);
}
__device__ __forceinline__ float gelu_f(float x) {
  return 0.5f * x * (1.0f + erff(x * 0.70710678118654752440f));
}
// async 16B global -> LDS (wave-uniform LDS base + lane*16)
__device__ __forceinline__ void gld16(const void* g, void* l) {
  __builtin_amdgcn_global_load_lds(
      (const __attribute__((address_space(1))) void*)g,
      (__attribute__((address_space(3))) void*)l, 16, 0, 0);
}

union H8 { f16x8 v; uint4 u; _Float16 h[8]; };
union H4 { uint2 u; _Float16 h[4]; };

__global__ void detect_k(const uint32_t* __restrict__ mark, int* __restrict__ FLAG) {
  if (threadIdx.x == 0) FLAG[0] = (mark[0] == 0x3F800000u) ? 1 : 0;
}

// transpose conv weight to wT[(c*3+t)*512 + d], f32. grid 126, block 256
__global__ __launch_bounds__(256) void wT_k(const void* __restrict__ w,
                                            float* __restrict__ wT,
                                            const int* __restrict__ FLAG) {
  const int isf = *FLAG;
  int idx = blockIdx.x * 256 + threadIdx.x;
  if (idx >= 63 * DD) return;
  int c3t = idx / DD;
  int d = idx - c3t * DD;
  wT[idx] = ldi(w, (long)d * 63 + c3t, isf);
}

// ---------------------------------------------------------------------------
// Conv1d circular embedding + fused split. grid (L/16, B), block 256
// writes X (region 0), XH/XL (region 67..134Mi) — disjoint, race-free.
// ---------------------------------------------------------------------------
__global__ __launch_bounds__(256) void conv_embed_k(
    const void* __restrict__ xe, const float* __restrict__ wT,
    float* __restrict__ X, _Float16* __restrict__ XH, _Float16* __restrict__ XL,
    const int* __restrict__ FLAG) {
  const int isf = *FLAG;
  int b = blockIdx.y;
  int l0 = blockIdx.x * 16;
  __shared__ float xs[18][21];
  int tid = threadIdx.x;
  for (int i = tid; i < 18 * 21; i += 256) {
    int r = i / 21, c = i % 21;
    int row = (l0 - 1 + r + LL) & (LL - 1);
    xs[r][c] = ldi(xe, ((long)b * LL + row) * 21 + c, isf);
  }
  __syncthreads();
  for (int d = tid; d < DD; d += 256) {
    float acc[16];
#pragma unroll
    for (int ll = 0; ll < 16; ll++) acc[ll] = 0.0f;
    for (int c = 0; c < 21; c++) {
#pragma unroll
      for (int t = 0; t < 3; t++) {
        float wv = wT[(c * 3 + t) * DD + d];  // coalesced
#pragma unroll
        for (int ll = 0; ll < 16; ll++) acc[ll] += wv * xs[t + ll][c];
      }
    }
    for (int ll = 0; ll < 16; ll++) {
      long idx = ((long)b * LL + l0 + ll) * DD + d;
      float v = acc[ll];
      X[idx] = v;
      _Float16 hv = (_Float16)v;
      XH[idx] = hv;
      XL[idx] = (_Float16)((v - (float)hv) * 512.0f);
    }
  }
}

// ---------------------------------------------------------------------------
// G'[r,c] = sum_f W1[f,r] * W2[f,c]   (f32 small GEMM)  grid (8,8), block 256
// ---------------------------------------------------------------------------
__global__ __launch_bounds__(256) void gt_k(
    const void* __restrict__ W1, const void* __restrict__ W2, long off,
    float* __restrict__ G, const int* __restrict__ FLAG) {
  const int isf = *FLAG;
  __shared__ float A1[64][65];
  __shared__ float A2[64][65];
  int c0 = blockIdx.x * 64, r0 = blockIdx.y * 64;
  int tid = threadIdx.x;
  int tx = tid & 15, ty = tid >> 4;
  float acc[4][4] = {};
  for (int f0 = 0; f0 < DD; f0 += 64) {
    for (int i = tid; i < 64 * 64; i += 256) {
      int r = i >> 6, c = i & 63;
      A1[r][c] = ldi(W1, off + (long)(f0 + r) * DD + r0 + c, isf);
      A2[r][c] = ldi(W2, off + (long)(f0 + r) * DD + c0 + c, isf);
    }
    __syncthreads();
    for (int f = 0; f < 64; f++) {
      float av[4], bv[4];
#pragma unroll
      for (int i = 0; i < 4; i++) av[i] = A1[f][ty * 4 + i];
#pragma unroll
      for (int j = 0; j < 4; j++) bv[j] = A2[f][tx * 4 + j];
#pragma unroll
      for (int i = 0; i < 4; i++)
#pragma unroll
        for (int j = 0; j < 4; j++) acc[i][j] = fmaf(av[i], bv[j], acc[i][j]);
    }
    __syncthreads();
  }
#pragma unroll
  for (int i = 0; i < 4; i++)
#pragma unroll
    for (int j = 0; j < 4; j++)
      G[(long)(r0 + ty * 4 + i) * DD + c0 + tx * 4 + j] = acc[i][j];
}

// split f32 -> (fp16 high, fp16 low*512). 8 elems/thread.
__global__ __launch_bounds__(256) void split_k(const float* __restrict__ src,
                                               _Float16* __restrict__ dh,
                                               _Float16* __restrict__ dl, int n) {
  long i = ((long)blockIdx.x * 256 + threadIdx.x) * 8;
  if (i >= n) return;
  float4 a = *(const float4*)(src + i);
  float4 b = *(const float4*)(src + i + 4);
  float x[8] = {a.x, a.y, a.z, a.w, b.x, b.y, b.z, b.w};
  H8 h, l;
#pragma unroll
  for (int j = 0; j < 8; j++) {
    _Float16 hv = (_Float16)x[j];
    h.h[j] = hv;
    l.h[j] = (_Float16)((x[j] - (float)hv) * 512.0f);
  }
  *(uint4*)(dh + i) = h.u;
  *(uint4*)(dl + i) = l.u;
}

// convert f32 -> fp16 (plain), 8 elems/thread
__global__ __launch_bounds__(256) void acvt_k(const float* __restrict__ src,
                                              _Float16* __restrict__ dst, int n) {
  long i = ((long)blockIdx.x * 256 + threadIdx.x) * 8;
  if (i >= n) return;
  float4 a = *(const float4*)(src + i);
  float4 b = *(const float4*)(src + i + 4);
  H8 r;
  r.h[0] = (_Float16)a.x; r.h[1] = (_Float16)a.y;
  r.h[2] = (_Float16)a.z; r.h[3] = (_Float16)a.w;
  r.h[4] = (_Float16)b.x; r.h[5] = (_Float16)b.y;
  r.h[6] = (_Float16)b.z; r.h[7] = (_Float16)b.w;
  *(uint4*)(dst + i) = r.u;
}

// all four Phase-B weights -> fp16 in one launch. grid 1280, block 256
__global__ __launch_bounds__(256) void wcvt6_k(
    const void* __restrict__ Wv, const void* __restrict__ Wo,
    const void* __restrict__ W1, const void* __restrict__ W2,
    long oW, long oF,
    _Float16* __restrict__ Wvh, _Float16* __restrict__ Woh,
    _Float16* __restrict__ W1h, _Float16* __restrict__ W2h,
    const int* __restrict__ FLAG) {
  const int isf = *FLAG;
  long e = ((long)blockIdx.x * 256 + threadIdx.x) * 8;
  const void* src; long soff; _Float16* dst;
  if (e < 262144) { src = Wv; soff = oW + e; dst = Wvh + e; }
  else if (e < 524288) { src = Wo; soff = oW + (e - 262144); dst = Woh + (e - 262144); }
  else if (e < 1572864) { src = W1; soff = oF + (e - 524288); dst = W1h + (e - 524288); }
  else { src = W2; soff = oF + (e - 1572864); dst = W2h + (e - 1572864); }
  H8 r;
  if (isf) {
    const float* s = (const float*)src + soff;
    float4 a = *(const float4*)s;
    float4 b = *(const float4*)(s + 4);
    r.h[0] = (_Float16)a.x; r.h[1] = (_Float16)a.y;
    r.h[2] = (_Float16)a.z; r.h[3] = (_Float16)a.w;
    r.h[4] = (_Float16)b.x; r.h[5] = (_Float16)b.y;
    r.h[6] = (_Float16)b.z; r.h[7] = (_Float16)b.w;
  } else {
    const u16* s = (const u16*)src + soff;
    uint4 u = *(const uint4*)s;
    r.h[0] = (_Float16)bf2f((u16)(u.x & 0xffff));
    r.h[1] = (_Float16)bf2f((u16)(u.x >> 16));
    r.h[2] = (_Float16)bf2f((u16)(u.y & 0xffff));
    r.h[3] = (_Float16)bf2f((u16)(u.y >> 16));
    r.h[4] = (_Float16)bf2f((u16)(u.z & 0xffff));
    r.h[5] = (_Float16)bf2f((u16)(u.z >> 16));
    r.h[6] = (_Float16)bf2f((u16)(u.w & 0xffff));
    r.h[7] = (_Float16)bf2f((u16)(u.w >> 16));
  }
  *(uint4*)(dst) = r.u;
}

// ---------------------------------------------------------------------------
// split-fp16 MFMA GEMM: Z = A @ W^T (split in/out). BK=32. (R9-verified)
// ---------------------------------------------------------------------------
__global__ __launch_bounds__(256) void gemm_z(
    const _Float16* __restrict__ Ah, const _Float16* __restrict__ Al,
    const _Float16* __restrict__ Bh, const _Float16* __restrict__ Bl,
    _Float16* __restrict__ Zh, _Float16* __restrict__ Zl,
    int M, int N, int K) {
  __shared__ __align__(16) _Float16 AsH[128 * 32];
  __shared__ __align__(16) _Float16 AsL[128 * 32];
  __shared__ __align__(16) _Float16 BsH[128 * 32];
  __shared__ __align__(16) _Float16 BsL[128 * 32];
  const int n0 = blockIdx.x * 128, m0 = blockIdx.y * 128;
  const int tid = threadIdx.x;
  const int lane = tid & 63, wvi = tid >> 6;
  const int wm = (wvi >> 1) * 64, wn = (wvi & 1) * 64;
  const int l15 = lane & 15, quad = lane >> 4;
  const int ib = wvi * 128 + lane;
  const int r0 = ib >> 2, r1 = r0 + 16;
  const int c0 = ((ib & 3) ^ ((r0 >> 1) & 3)) * 8;
  const int c1 = ((ib & 3) ^ ((r1 >> 1) & 3)) * 8;
  const int lb0 = wvi * 1024, lb1 = wvi * 1024 + 512;
  const long ga0 = (long)(m0 + r0) * K + c0;
  const long ga1 = (long)(m0 + r1) * K + c1;
  const long gb0 = (long)(n0 + r0) * K + c0;
  const long gb1 = (long)(n0 + r1) * K + c1;
  f32x4 aM[4][4], aC[4][4];
#pragma unroll
  for (int i = 0; i < 4; i++)
#pragma unroll
    for (int j = 0; j < 4; j++) {
      aM[i][j] = (f32x4){0.f, 0.f, 0.f, 0.f};
      aC[i][j] = (f32x4){0.f, 0.f, 0.f, 0.f};
    }
  for (int k0 = 0; k0 < K; k0 += 32) {
    __syncthreads();
    gld16(Ah + ga0 + k0, AsH + lb0);
    gld16(Ah + ga1 + k0, AsH + lb1);
    gld16(Al + ga0 + k0, AsL + lb0);
    gld16(Al + ga1 + k0, AsL + lb1);
    gld16(Bh + gb0 + k0, BsH + lb0);
    gld16(Bh + gb1 + k0, BsH + lb1);
    gld16(Bl + gb0 + k0, BsL + lb0);
    gld16(Bl + gb1 + k0, BsL + lb1);
    __syncthreads();
    f16x8 fah[4], fal[4], fbh[4], fbl[4];
#pragma unroll
    for (int mi = 0; mi < 4; mi++) {
      int r = wm + mi * 16 + l15;
      int o = r * 32 + ((quad ^ ((r >> 1) & 3)) * 8);
      fah[mi] = *(const f16x8*)&AsH[o];
      fal[mi] = *(const f16x8*)&AsL[o];
    }
#pragma unroll
    for (int ni = 0; ni < 4; ni++) {
      int r = wn + ni * 16 + l15;
      int o = r * 32 + ((quad ^ ((r >> 1) & 3)) * 8);
      fbh[ni] = *(const f16x8*)&BsH[o];
      fbl[ni] = *(const f16x8*)&BsL[o];
    }
#pragma unroll
    for (int mi = 0; mi < 4; mi++)
#pragma unroll
      for (int ni = 0; ni < 4; ni++) {
        aM[mi][ni] = __builtin_amdgcn_mfma_f32_16x16x32_f16(
            fah[mi], fbh[ni], aM[mi][ni], 0, 0, 0);
        aC[mi][ni] = __builtin_amdgcn_mfma_f32_16x16x32_f16(
            fah[mi], fbl[ni], aC[mi][ni], 0, 0, 0);
        aC[mi][ni] = __builtin_amdgcn_mfma_f32_16x16x32_f16(
            fal[mi], fbh[ni], aC[mi][ni], 0, 0, 0);
      }
  }
#pragma unroll
  for (int mi = 0; mi < 4; mi++) {
    int rowg = m0 + wm + mi * 16 + quad * 4;
#pragma unroll
    for (int ni = 0; ni < 4; ni++) {
      int colg = n0 + wn + ni * 16 + l15;
#pragma unroll
      for (int rr = 0; rr < 4; rr++) {
        long off = (long)(rowg + rr) * N + colg;
        float z = aM[mi][ni][rr] + aC[mi][ni][rr] * (1.0f / 512.0f);
        _Float16 zh = (_Float16)z;
        Zh[off] = zh;
        Zl[off] = (_Float16)((z - (float)zh) * 512.0f);
      }
    }
  }
}

// ---------------------------------------------------------------------------
// split-fp16 MFMA Z.X^T + fused wrapped-diagonal mean reduce. BK=32.
// ---------------------------------------------------------------------------
__global__ __launch_bounds__(256) void qkmv_hl(
    const _Float16* __restrict__ Zh, const _Float16* __restrict__ Zl,
    const _Float16* __restrict__ Xh, const _Float16* __restrict__ Xl,
    float* __restrict__ MV) {
  __shared__ __align__(16) _Float16 AsH[128 * 32];
  __shared__ __align__(16) _Float16 AsL[128 * 32];
  __shared__ __align__(16) _Float16 BsH[128 * 32];
  __shared__ __align__(16) _Float16 BsL[128 * 32];
  __shared__ float diag[255];
  const int bz = blockIdx.z;
  const long bb = (long)bz * LL * DD;
  const int n0 = blockIdx.x * 128, m0 = blockIdx.y * 128;
  const int tid = threadIdx.x;
  const int lane = tid & 63, wvi = tid >> 6;
  const int wm = (wvi >> 1) * 64, wn = (wvi & 1) * 64;
  const int l15 = lane & 15, quad = lane >> 4;
  const int ib = wvi * 128 + lane;
  const int r0 = ib >> 2, r1 = r0 + 16;
  const int c0 = ((ib & 3) ^ ((r0 >> 1) & 3)) * 8;
  const int c1 = ((ib & 3) ^ ((r1 >> 1) & 3)) * 8;
  const int lb0 = wvi * 1024, lb1 = wvi * 1024 + 512;
  const long ga0 = bb + (long)(m0 + r0) * DD + c0;
  const long ga1 = bb + (long)(m0 + r1) * DD + c1;
  const long gb0 = bb + (long)(n0 + r0) * DD + c0;
  const long gb1 = bb + (long)(n0 + r1) * DD + c1;
  if (tid < 255) diag[tid] = 0.0f;
  f32x4 aM[4][4], aC[4][4];
#pragma unroll
  for (int i = 0; i < 4; i++)
#pragma unroll
    for (int j = 0; j < 4; j++) {
      aM[i][j] = (f32x4){0.f, 0.f, 0.f, 0.f};
      aC[i][j] = (f32x4){0.f, 0.f, 0.f, 0.f};
    }
  for (int k0 = 0; k0 < DD; k0 += 32) {
    __syncthreads();
    gld16(Zh + ga0 + k0, AsH + lb0);
    gld16(Zh + ga1 + k0, AsH + lb1);
    gld16(Zl + ga0 + k0, AsL + lb0);
    gld16(Zl + ga1 + k0, AsL + lb1);
    gld16(Xh + gb0 + k0, BsH + lb0);
    gld16(Xh + gb1 + k0, BsH + lb1);
    gld16(Xl + gb0 + k0, BsL + lb0);
    gld16(Xl + gb1 + k0, BsL + lb1);
    __syncthreads();
    f16x8 fah[4], fal[4], fbh[4], fbl[4];
#pragma unroll
    for (int mi = 0; mi < 4; mi++) {
      int r = wm + mi * 16 + l15;
      int o = r * 32 + ((quad ^ ((r >> 1) & 3)) * 8);
      fah[mi] = *(const f16x8*)&AsH[o];
      fal[mi] = *(const f16x8*)&AsL[o];
    }
#pragma unroll
    for (int ni = 0; ni < 4; ni++) {
      int r = wn + ni * 16 + l15;
      int o = r * 32 + ((quad ^ ((r >> 1) & 3)) * 8);
      fbh[ni] = *(const f16x8*)&BsH[o];
      fbl[ni] = *(const f16x8*)&BsL[o];
    }
#pragma unroll
    for (int mi = 0; mi < 4; mi++)
#pragma unroll
      for (int ni = 0; ni < 4; ni++) {
        aM[mi][ni] = __builtin_amdgcn_mfma_f32_16x16x32_f16(
            fah[mi], fbh[ni], aM[mi][ni], 0, 0, 0);
        aC[mi][ni] = __builtin_amdgcn_mfma_f32_16x16x32_f16(
            fah[mi], fbl[ni], aC[mi][ni], 0, 0, 0);
        aC[mi][ni] = __builtin_amdgcn_mfma_f32_16x16x32_f16(
            fal[mi], fbh[ni], aC[mi][ni], 0, 0, 0);
      }
  }
#pragma unroll
  for (int g = -3; g <= 3; g++) {
#pragma unroll
    for (int rr = 0; rr < 4; rr++) {
      float s = 0.0f;
#pragma unroll
      for (int mi = 0; mi < 4; mi++) {
        int ni = mi - g;
        if (ni >= 0 && ni < 4)
          s += aM[mi][ni][rr] + aC[mi][ni][rr] * (1.0f / 512.0f);
      }
      int d = 127 + (wm - wn) + g * 16 + quad * 4 + rr - l15;
      atomicAdd(&diag[d], s);
    }
  }
  __syncthreads();
  if (tid < 255) {
    int tau = (m0 - n0 + tid - 127 + LL) & (LL - 1);
    atomicAdd(&MV[(long)bz * LL + tau], diag[tid] * (1.0f / 512.0f));
  }
}

// ---------------------------------------------------------------------------
// fp16 MFMA GEMM, BK=64: C[M,N] = act( A[M,K] @ W[N,K]^T + bias + R )
// FLAGS: 1=bias 2=gelu 4=residual 8=out-fp16
// ---------------------------------------------------------------------------
template <int FLAGS>
__global__ __launch_bounds__(256) void gemm_h(
    const _Float16* __restrict__ A, const _Float16* __restrict__ W,
    const void* __restrict__ biasBase, long bOff,
    const float* __restrict__ R, void* __restrict__ Cout,
    int M, int N, int K, const int* __restrict__ FLAG) {
  constexpr bool HAS_BIAS = (FLAGS & 1) != 0;
  constexpr bool DO_GELU = (FLAGS & 2) != 0;
  constexpr bool DO_RES = (FLAGS & 4) != 0;
  constexpr bool OUT_H = (FLAGS & 8) != 0;
  __shared__ __align__(16) _Float16 As[128 * 64];
  __shared__ __align__(16) _Float16 Bs[128 * 64];
  const int n0 = blockIdx.x * 128, m0 = blockIdx.y * 128;
  const int tid = threadIdx.x;
  const int lane = tid & 63, wvi = tid >> 6;
  const int wm = (wvi >> 1) * 64, wn = (wvi & 1) * 64;
  const int l15 = lane & 15, quad = lane >> 4;
  // staging: block ib -> row ib>>3, LDS seg p = ib&7;
  // global seg gs = (p&4) | ((p&3) ^ ((row>>1)&3)).
  const _Float16* gA[4];
  const _Float16* gB[4];
  int ldsOff[4];
#pragma unroll
  for (int j = 0; j < 4; j++) {
    int ib = wvi * 256 + j * 64 + lane;
    int row = ib >> 3, p = ib & 7;
    int gc = ((p & 4) | ((p & 3) ^ ((row >> 1) & 3))) * 8;
    gA[j] = A + (long)(m0 + row) * K + gc;
    gB[j] = W + (long)(n0 + row) * K + gc;
    ldsOff[j] = wvi * 2048 + j * 512;
  }
  f32x4 acc[4][4];
#pragma unroll
  for (int i = 0; i < 4; i++)
#pragma unroll
    for (int j = 0; j < 4; j++) acc[i][j] = (f32x4){0.f, 0.f, 0.f, 0.f};
  for (int k0 = 0; k0 < K; k0 += 64) {
    __syncthreads();
#pragma unroll
    for (int j = 0; j < 4; j++) gld16(gA[j] + k0, As + ldsOff[j]);
#pragma unroll
    for (int j = 0; j < 4; j++) gld16(gB[j] + k0, Bs + ldsOff[j]);
    __syncthreads();
#pragma unroll
    for (int ks = 0; ks < 2; ks++) {
      f16x8 af[4], bfr[4];
#pragma unroll
      for (int mi = 0; mi < 4; mi++) {
        int r = wm + mi * 16 + l15;
        af[mi] = *(const f16x8*)&As[r * 64 + (ks * 4 + (quad ^ ((r >> 1) & 3))) * 8];
      }
#pragma unroll
      for (int ni = 0; ni < 4; ni++) {
        int r = wn + ni * 16 + l15;
        bfr[ni] = *(const f16x8*)&Bs[r * 64 + (ks * 4 + (quad ^ ((r >> 1) & 3))) * 8];
      }
#pragma unroll
      for (int mi = 0; mi < 4; mi++)
#pragma unroll
        for (int ni = 0; ni < 4; ni++)
          acc[mi][ni] = __builtin_amdgcn_mfma_f32_16x16x32_f16(
              af[mi], bfr[ni], acc[mi][ni], 0, 0, 0);
    }
  }
  float bcol[4];
  if constexpr (HAS_BIAS) {
    const int isf = *FLAG;
#pragma unroll
    for (int ni = 0; ni < 4; ni++)
      bcol[ni] = ldi(biasBase, bOff + n0 + wn + ni * 16 + l15, isf);
  }
#pragma unroll
  for (int mi = 0; mi < 4; mi++) {
    int rowg = m0 + wm + mi * 16 + quad * 4;
#pragma unroll
    for (int ni = 0; ni < 4; ni++) {
      int colg = n0 + wn + ni * 16 + l15;
#pragma unroll
      for (int rr = 0; rr < 4; rr++) {
        long off = (long)(rowg + rr) * N + colg;
        float v = acc[mi][ni][rr];
        if constexpr (HAS_BIAS) v += bcol[ni];
        if constexpr (DO_RES) v += R[off];
        if constexpr (DO_GELU) v = gelu_f(v);
        if constexpr (OUT_H) ((_Float16*)Cout)[off] = (_Float16)v;
        else ((float*)Cout)[off] = v;
      }
    }
  }
}

// ---------------------------------------------------------------------------
// top-6 of MV[b,:] + softmax.  grid (32), block 256
// ---------------------------------------------------------------------------
__global__ __launch_bounds__(256) void topk_k(const float* __restrict__ MV,
                                              float* __restrict__ WGT,
                                              int* __restrict__ DLY) {
  int b = blockIdx.x;
  __shared__ float vals[LL];
  __shared__ float rv[256];
  __shared__ int ri[256];
  __shared__ float selv[6];
  int tid = threadIdx.x;
  for (int i = tid; i < LL; i += 256) vals[i] = MV[(long)b * LL + i];
  __syncthreads();
  for (int it = 0; it < 6; it++) {
    float bv = -1e30f;
    int bi = LL - 1;
    for (int i = tid; i < LL; i += 256) {
      float v = vals[i];
      if (v > bv || (v == bv && i < bi)) { bv = v; bi = i; }
    }
    rv[tid] = bv; ri[tid] = bi;
    __syncthreads();
    for (int st = 128; st > 0; st >>= 1) {
      if (tid < st) {
        float ov = rv[tid + st]; int oi = ri[tid + st];
        if (ov > rv[tid] || (ov == rv[tid] && oi < ri[tid])) {
          rv[tid] = ov; ri[tid] = oi;
        }
      }
      __syncthreads();
    }
    if (tid == 0) {
      selv[it] = rv[0];
      DLY[b * 6 + it] = ri[0];
      vals[ri[0]] = -1e30f;
    }
    __syncthreads();
  }
  if (tid == 0) {
    float mx = selv[0];
    float e[6], s = 0.0f;
    for (int i = 0; i < 6; i++) { e[i] = expf(selv[i] - mx); s += e[i]; }
    for (int i = 0; i < 6; i++) WGT[b * 6 + i] = e[i] / s;
  }
}

// ---------------------------------------------------------------------------
// time-delay aggregation, fp16 in/out (chunk-local): grid (1024, NB), block 128
// ---------------------------------------------------------------------------
__global__ __launch_bounds__(128) void agg_k(const _Float16* __restrict__ V,
                                             const float* __restrict__ WGT,
                                             const int* __restrict__ DLY,
                                             _Float16* __restrict__ O) {
  int l = blockIdx.x, b = blockIdx.y;
  int tid = threadIdx.x;
  float w[6]; int dl[6];
#pragma unroll
  for (int i = 0; i < 6; i++) { w[i] = WGT[b * 6 + i]; dl[i] = DLY[b * 6 + i]; }
  long base = (long)b * LL * DD;
  int d = tid * 4;
  float a0 = 0, a1 = 0, a2 = 0, a3 = 0;
#pragma unroll
  for (int i = 0; i < 6; i++) {
    int row = (l + dl[i]) & (LL - 1);
    H4 t; t.u = *(const uint2*)&V[base + (long)row * DD + d];
    a0 += w[i] * (float)t.h[0];
    a1 += w[i] * (float)t.h[1];
    a2 += w[i] * (float)t.h[2];
    a3 += w[i] * (float)t.h[3];
  }
  H4 r;
  r.h[0] = (_Float16)a0; r.h[1] = (_Float16)a1;
  r.h[2] = (_Float16)a2; r.h[3] = (_Float16)a3;
  *(uint2*)&O[base + (long)l * DD + d] = r.u;
}

// ---------------------------------------------------------------------------
// series_decomp residual (f32 out only, race-free). grid (2, 16, 32), block 256
// ---------------------------------------------------------------------------
__global__ __launch_bounds__(256) void decomp_k(const float* __restrict__ Xin,
                                                float* __restrict__ Out) {
  int d = blockIdx.x * 256 + threadIdx.x;
  int l0 = blockIdx.y * 64;
  int b = blockIdx.z;
  const float* xb = Xin + (long)b * LL * DD + d;
  float* ob = Out + (long)b * LL * DD + d;
  float wsum = 0.0f;
  for (int j = l0 - 12; j <= l0 + 12; j++) {
    int jj = min(max(j, 0), LL - 1);
    wsum += xb[(long)jj * DD];
  }
  for (int l = l0; l < l0 + 64; l++) {
    float xv = xb[(long)l * DD];
    ob[(long)l * DD] = xv - wsum * (1.0f / 25.0f);
    int ja = min(l + 13, LL - 1);
    int jr = max(l - 12, 0);
    wsum += xb[(long)ja * DD] - xb[(long)jr * DD];
  }
}

// special layernorm. grid (1024,32), block 256
__global__ __launch_bounds__(256) void ln_k(const float* __restrict__ X,
                                            const void* __restrict__ g,
                                            const void* __restrict__ be,
                                            float* __restrict__ XHo,
                                            const int* __restrict__ FLAG) {
  const int isf = *FLAG;
  int l = blockIdx.x, b = blockIdx.y;
  const float* xr = X + ((long)b * LL + l) * DD;
  int tid = threadIdx.x;
  float x0 = xr[tid], x1 = xr[tid + 256];
  __shared__ float rs[256], rq[256];
  rs[tid] = x0 + x1;
  rq[tid] = x0 * x0 + x1 * x1;
  __syncthreads();
  for (int st = 128; st > 0; st >>= 1) {
    if (tid < st) { rs[tid] += rs[tid + st]; rq[tid] += rq[tid + st]; }
    __syncthreads();
  }
  float mu = rs[0] * (1.0f / 512.0f);
  float var = rq[0] * (1.0f / 512.0f) - mu * mu;
  float rstd = rsqrtf(var + 1e-5f);
  float* o = XHo + ((long)b * LL + l) * DD;
  o[tid] = (x0 - mu) * rstd * ldi(g, tid, isf) + ldi(be, tid, isf);
  o[tid + 256] = (x1 - mu) * rstd * ldi(g, tid + 256, isf) + ldi(be, tid + 256, isf);
}

// colmean. grid (2,32), block 256
__global__ __launch_bounds__(256) void colmean_k(const float* __restrict__ XHo,
                                                 float* __restrict__ CM) {
  int d = blockIdx.x * 256 + threadIdx.x;
  int b = blockIdx.y;
  const float* p = XHo + (long)b * LL * DD + d;
  float s = 0.0f;
  for (int l = 0; l < LL; l++) s += p[(long)l * DD];
  CM[(long)b * DD + d] = s * (1.0f / 1024.0f);
}

// OUT = gelu(XH - CM) * mark. grid (1024,32), block 256
__global__ __launch_bounds__(256) void geluout_k(const float* __restrict__ XHo,
                                                 const float* __restrict__ CM,
                                                 const void* __restrict__ mark,
                                                 float* __restrict__ OUT,
                                                 const int* __restrict__ FLAG) {
  const int isf = *FLAG;
  int l = blockIdx.x, b = blockIdx.y;
  int tid = threadIdx.x;
  float mk = ldi(mark, (long)b * LL + l, isf);
  long off = ((long)b * LL + l) * DD;
#pragma unroll
  for (int h = 0; h < 2; h++) {
    int d = tid + h * 256;
    float v = XHo[off + d] - CM[(long)b * DD + d];
    OUT[off + d] = gelu_f(v) * mk;
  }
}

// proj stage 1. grid (16, 10, 32), block 256
__global__ __launch_bounds__(256) void proj1_k(const float* __restrict__ OUT,
                                               const void* __restrict__ Wp,
                                               float* __restrict__ PB,
                                               const int* __restrict__ FLAG) {
  const int isf = *FLAG;
  int chunk = blockIdx.x, n = blockIdx.y, b = blockIdx.z;
  long e0 = (long)chunk * 32768;
  const float* xb = OUT + (long)b * 524288 + e0;
  long wbase = (long)n * 524288 + e0;
  int tid = threadIdx.x;
  float s = 0.0f;
  if (isf) {
    const float* wr = (const float*)Wp + wbase;
    for (int i = tid * 4; i < 32768; i += 1024) {
      float4 x = *(const float4*)&xb[i];
      float4 w = *(const float4*)&wr[i];
      s += x.x * w.x + x.y * w.y + x.z * w.z + x.w * w.w;
    }
  } else {
    const u16* wr = (const u16*)Wp + wbase;
    for (int i = tid * 4; i < 32768; i += 1024) {
      float4 x = *(const float4*)&xb[i];
      uint2 u = *(const uint2*)&wr[i];
      s += x.x * bf2f((u16)(u.x & 0xffff)) + x.y * bf2f((u16)(u.x >> 16)) +
           x.z * bf2f((u16)(u.y & 0xffff)) + x.w * bf2f((u16)(u.y >> 16));
    }
  }
  __shared__ float red[256];
  red[tid] = s;
  __syncthreads();
  for (int st = 128; st > 0; st >>= 1) {
    if (tid < st) red[tid] += red[tid + st];
    __syncthreads();
  }
  if (tid == 0) PB[((long)b * 10 + n) * 16 + chunk] = red[0];
}

// proj stage 2: logits -> out (dtype per FLAG). grid (1), block 320
__global__ __launch_bounds__(320) void proj2_k(const float* __restrict__ PB,
                                               const void* __restrict__ bp,
                                               void* __restrict__ out,
                                               const int* __restrict__ FLAG) {
  const int isf = *FLAG;
  int id = threadIdx.x;
  int b = id / 10, n = id % 10;
  float s = ldi(bp, n, isf);
  for (int c = 0; c < 16; c++) s += PB[((long)b * 10 + n) * 16 + c];
  if (isf) ((float*)out)[b * 10 + n] = s;
  else ((u16*)out)[b * 10 + n] = f2bf(s);
}

// ---------------------------------------------------------------------------
extern "C" void kernel_launch(void* const* d_in, const int* in_sizes, int n_in,
                              void* d_out, int out_size, void* d_ws, size_t ws_size,
                              hipStream_t stream) {
  const void* xe = d_in[0];
  const void* mark = d_in[1];
  const void* cw = d_in[2];
  const void* Wq = d_in[3];
  const void* Wk = d_in[5];
  const void* Wv = d_in[7];
  const void* bv = d_in[8];
  const void* Wo = d_in[9];
  const void* bo = d_in[10];
  const void* Wff1 = d_in[11];
  const void* Wff2 = d_in[12];
  const void* lng = d_in[13];
  const void* lnb = d_in[14];
  const void* Wp = d_in[15];
  const void* bp = d_in[16];

  char* ws = (char*)d_ws;
  float* X      = (float*)(ws + 0L);               // 64 MiB f32 residual
  _Float16* XH  = (_Float16*)(ws + 67108864L);     // fp16 X-high, 32 MiB
  _Float16* XL  = (_Float16*)(ws + 100663296L);    // fp16 X-low*512 / AGh
  _Float16* AGh = (_Float16*)(ws + 100663296L);
  _Float16* ZH  = (_Float16*)(ws + 134217728L);    // Z-high chunk, 4 MiB
  _Float16* ZL  = (_Float16*)(ws + 138412032L);    // Z-low chunk, 4 MiB
  _Float16* Ph  = (_Float16*)(ws + 134217728L);    // Phase B: 8 MiB chunk
  float* G32    = (float*)(ws + 142606336L);       // 1 MiB (also wT for conv)
  float* wT     = (float*)(ws + 142606336L);
  _Float16* GH  = (_Float16*)(ws + 143654912L);    // 0.5 MiB
  _Float16* GL  = (_Float16*)(ws + 144179200L);    // 0.5 MiB
  _Float16* Wvh = (_Float16*)(ws + 142606336L);    // Phase B overlays
  _Float16* Woh = (_Float16*)(ws + 143130624L);
  _Float16* W1h = (_Float16*)(ws + 143654912L);    // 2 MiB
  _Float16* W2h = (_Float16*)(ws + 145752064L);    // 2 MiB
  float* MV  = (float*)(ws + 147849216L);
  float* WGT = (float*)(ws + 147980288L);
  int*   DLY = (int*)(ws + 147981312L);
  float* CM  = (float*)(ws + 147982336L);
  float* PB  = (float*)(ws + 148047872L);
  int*  FLAG = (int*)(ws + 148068352L);
  float* S2  = (float*)(ws + 67108864L);           // FFN XD f32 / final XH
  _Float16* Hb = (_Float16*)X;                     // FFN hidden (X dead)

  const long AD = (long)LL * DD;   // 524288
  const int M = BB * LL;           // 32768

  detect_k<<<1, 64, 0, stream>>>((const uint32_t*)mark, FLAG);
  wT_k<<<126, 256, 0, stream>>>(cw, wT, FLAG);
  conv_embed_k<<<dim3(64, 32), 256, 0, stream>>>(xe, wT, X, XH, XL, FLAG);

  for (int l = 0; l < 3; l++) {
    const long oW = (long)l * DD * DD;
    const long oB = (long)l * DD;
    const long oF = (long)l * DFF * DD;

    // ---- Phase A: delay selection via G-trick + fp16x2 split MFMA ----
    gt_k<<<dim3(8, 8), 256, 0, stream>>>(Wk, Wq, oW, G32, FLAG);
    split_k<<<128, 256, 0, stream>>>(G32, GH, GL, 262144);
    hipMemsetAsync(MV, 0, (long)BB * LL * sizeof(float), stream);
    for (int cb = 0; cb < 8; cb++) {
      const long co = (long)cb * 4 * AD;
      gemm_z<<<dim3(4, 32), 256, 0, stream>>>(
          XH + co, XL + co, GH, GL, ZH, ZL, 4096, DD, DD);
      qkmv_hl<<<dim3(8, 8, 4), 256, 0, stream>>>(
          ZH, ZL, XH + co, XL + co, MV + (long)cb * 4 * LL);
    }
    topk_k<<<32, 256, 0, stream>>>(MV, WGT, DLY);

    // ---- Phase B: fp16 MFMA for V / agg / Wo / FFN ----
    wcvt6_k<<<1280, 256, 0, stream>>>(Wv, Wo, Wff1, Wff2, oW, oF,
                                      Wvh, Woh, W1h, W2h, FLAG);

    // V (fp16) per 8-batch chunk -> Ph (over ZH/ZL, dead), agg -> AGh (over XL)
    for (int cb = 0; cb < 4; cb++) {
      const _Float16* xh = XH + (long)cb * 8 * AD;
      gemm_h<1 | 8><<<dim3(4, 64), 256, 0, stream>>>(
          xh, Wvh, bv, oB, nullptr, Ph, 8192, DD, DD, FLAG);
      agg_k<<<dim3(1024, 8), 128, 0, stream>>>(
          Ph, WGT + cb * 48, DLY + cb * 48, AGh + (long)cb * 8 * AD);
    }

    // X = X + AGh @ Wo^T + bo (full M, in-place residual)
    gemm_h<1 | 4><<<dim3(4, 256), 256, 0, stream>>>(
        AGh, Woh, bo, oB, X, X, M, DD, DD, FLAG);

    // x = decomp(X) -> S2 f32 (over XH/AGh, both dead)
    decomp_k<<<dim3(2, 16, 32), 256, 0, stream>>>(X, S2);

    // FFN per 8-batch chunk: S2 chunk -> fp16 Ph; hidden -> Hb (X region);
    // S2chunk = S2chunk + (gelu-hidden) @ W2^T
    for (int cb = 0; cb < 4; cb++) {
      float* xd = S2 + (long)cb * 8 * AD;
      acvt_k<<<2048, 256, 0, stream>>>(xd, Ph, 4194304);
      gemm_h<2 | 8><<<dim3(16, 64), 256, 0, stream>>>(
          Ph, W1h, nullptr, 0, nullptr, Hb, 8192, DFF, DD, FLAG);
      gemm_h<4><<<dim3(4, 64), 256, 0, stream>>>(
          Hb, W2h, nullptr, 0, xd, xd, 8192, DD, DFF, FLAG);
    }

    // x = decomp(S2) -> X; then split X -> (XH, XL) for next layer's Phase A
    decomp_k<<<dim3(2, 16, 32), 256, 0, stream>>>(S2, X);
    if (l < 2) split_k<<<8192, 256, 0, stream>>>(X, XH, XL, 16777216);
  }

  // final special layernorm + gelu + mask + projection
  ln_k<<<dim3(1024, 32), 256, 0, stream>>>(X, lng, lnb, S2, FLAG);
  colmean_k<<<dim3(2, 32), 256, 0, stream>>>(S2, CM);
  geluout_k<<<dim3(1024, 32), 256, 0, stream>>>(S2, CM, mark, X, FLAG);
  proj1_k<<<dim3(16, 10, 32), 256, 0, stream>>>(X, Wp, PB, FLAG);
  proj2_k<<<1, 320, 0, stream>>>(PB, bp, d_out, FLAG);
}